// Round 18
// baseline (155.487 us; speedup 1.0000x reference)
//
#include <hip/hip_runtime.h>
#include <hip/hip_bf16.h>
#include <stdint.h>

typedef __attribute__((ext_vector_type(4)))  float  f32x4;
typedef __attribute__((ext_vector_type(16))) float  f32x16;
typedef __attribute__((ext_vector_type(8)))  __bf16 bf16x8;
typedef __attribute__((ext_vector_type(4)))  float  float4_t;
typedef __attribute__((ext_vector_type(4)))  int    int4_t;

// ---------- helpers ----------

__device__ __forceinline__ short f2bf(float f) {
  uint32_t u = __builtin_bit_cast(uint32_t, f);
  return (short)((u + 0x7FFFu + ((u >> 16) & 1u)) >> 16);
}

__device__ __forceinline__ void gload16(const void* g, void* l) {
  __builtin_amdgcn_global_load_lds(
      (const __attribute__((address_space(1))) void*)g,
      (__attribute__((address_space(3))) void*)l, 16, 0, 0);
}

__device__ __forceinline__ bf16x8 frag_w0(unsigned int w0) {
  union { unsigned int u[4]; bf16x8 v; } t;
  t.u[0] = w0; t.u[1] = 0; t.u[2] = 0; t.u[3] = 0;
  return t.v;
}

// ---------- mask compaction scan ----------
// Per batch (4 blocks): pidx[s] = (compacted_index << 1) | keep; lens[b] = #kept.
// Also zeroes the compacted K tail rows [len, ceil64(len)) and VT tail cols,
// so attention's padding keys get score = bias(-14400) -> p = exp2 -> exact 0.

__global__ __launch_bounds__(256) void mask_scan(
    const int* __restrict__ mask, int* __restrict__ pidx, int* __restrict__ lens,
    short* __restrict__ kb, short* __restrict__ vtb)
{
  const int b   = blockIdx.x;
  const int tid = threadIdx.x;
  const int lane = tid & 63, wv = tid >> 6;
  __shared__ int wtot[4];
  const int* mb = mask + (b << 11);
  int4_t a = reinterpret_cast<const int4_t*>(mb)[tid * 2];
  int4_t c = reinterpret_cast<const int4_t*>(mb)[tid * 2 + 1];
  int m[8] = {a[0] ? 1 : 0, a[1] ? 1 : 0, a[2] ? 1 : 0, a[3] ? 1 : 0,
              c[0] ? 1 : 0, c[1] ? 1 : 0, c[2] ? 1 : 0, c[3] ? 1 : 0};
  int tsum = 0;
#pragma unroll
  for (int j = 0; j < 8; ++j) tsum += m[j];
  int inc = tsum;
#pragma unroll
  for (int d = 1; d < 64; d <<= 1) {
    int t = __shfl_up(inc, d);
    if (lane >= d) inc += t;
  }
  if (lane == 63) wtot[wv] = inc;
  __syncthreads();
  int woff = 0;
#pragma unroll
  for (int w = 0; w < 3; ++w) if (w < wv) woff += wtot[w];
  int run = woff + inc - tsum;
#pragma unroll
  for (int j = 0; j < 8; ++j) {
    pidx[(b << 11) + tid * 8 + j] = (run << 1) | m[j];
    run += m[j];
  }
  const int total = wtot[0] + wtot[1] + wtot[2] + wtot[3];
  if (tid == 0) lens[b] = total;
  const int pad  = (total + 63) & ~63;
  const int tail = pad - total;
  if (tail == 0) return;
  for (int h = 0; h < 12; ++h) {
    // K tail rows are contiguous: [bh][s][64], s in [total,pad)
    uint64_t* kbase = reinterpret_cast<uint64_t*>(
        kb + ((((int64_t)(b * 12 + h)) << 11) + total) * 64);
    for (int i = tid; i < tail * 8; i += 256) kbase[i] = 0;
    // VT tail cols: [bh][d][2048], col in [total,pad)
    short* vbase = vtb + (((int64_t)(b * 12 + h)) * 64 << 11);
    for (int i = tid; i < 64 * tail; i += 256) {
      int d = i / tail, s = total + i % tail;
      vbase[(d << 11) + s] = 0;
    }
  }
}

// ---------- fused fp32 -> bf16 convert (all three inputs, one launch) ----------
// region sizes in float4 units: x 1572864, w_qkv 442368, w_out 147456

__global__ void cvt_all(const float* __restrict__ x,   short* __restrict__ xo,
                        const float* __restrict__ w1,  short* __restrict__ w1o,
                        const float* __restrict__ w2,  short* __restrict__ w2o) {
  int i = blockIdx.x * 256 + threadIdx.x;
  const float* src; short* dst;
  if (i < 1572864)      { src = x;  dst = xo; }
  else if (i < 2015232) { src = w1; dst = w1o; i -= 1572864; }
  else if (i < 2162688) { src = w2; dst = w2o; i -= 2015232; }
  else return;
  float4_t v = reinterpret_cast<const float4_t*>(src)[i];
  union { short s[4]; uint64_t u; } o;
  o.s[0] = f2bf(v[0]); o.s[1] = f2bf(v[1]);
  o.s[2] = f2bf(v[2]); o.s[3] = f2bf(v[3]);
  reinterpret_cast<uint64_t*>(dst)[i] = o.u;
}

// ---------- 128x128 bf16 GEMM, C = A[M,K] * W[N,K]^T (R16 structure) ----------
// BK=32, 3-buffer LDS pipeline (48 KB -> 3 blocks/CU), counted vmcnt(4),
// loads 2 tiles ahead; 2-way-free XOR column swizzle on global source +
// frag read. XCD-chunked block swizzle.
// MODE 0: QKV scatter with per-batch K/V COMPACTION via pidx; MODE 1: fp32 C.

template<int MODE>
__global__ __launch_bounds__(256) void gemm_bt(
    const short* __restrict__ A, const short* __restrict__ Bw,
    float* __restrict__ Cf,
    short* __restrict__ qb, short* __restrict__ kb, short* __restrict__ vtb,
    const int* __restrict__ pidx,
    int M, int N, int K)
{
  __shared__ __align__(16) short As[3][128 * 32];
  __shared__ __align__(16) short Bs[3][128 * 32];
  const int tid  = threadIdx.x;
  const int lane = tid & 63;
  const int wave = tid >> 6;
  const int ntn  = N >> 7;
  const int cpx  = gridDim.x >> 3;
  const int nid  = (blockIdx.x & 7) * cpx + (blockIdx.x >> 3);
  const int bm   = nid / ntn;
  const int bn   = nid % ntn;
  const int wr   = wave >> 1, wc = wave & 1;
  const int l16  = lane & 15, lhi = lane >> 4;

  f32x4 acc[4][4] = {};

  const int srow = lane >> 2;
  const int sg   = lane & 3;
  const int sgx  = (sg ^ ((srow >> 1) & 3)) * 8;
  const short* aG = A  + (int64_t)(bm * 128) * K;
  const short* bG = Bw + (int64_t)(bn * 128) * K;
  const int nt = K >> 5;

  auto STAGE = [&](int buf, int t) {
    const int k0 = t * 32;
#pragma unroll
    for (int i = 0; i < 2; ++i) {
      int rr = wave * 32 + i * 16 + srow;
      gload16(aG + (int64_t)rr * K + k0 + sgx,
              &As[buf][(wave * 32 + i * 16) * 32 + lane * 8]);
      gload16(bG + (int64_t)rr * K + k0 + sgx,
              &Bs[buf][(wave * 32 + i * 16) * 32 + lane * 8]);
    }
  };

  STAGE(0, 0);
  STAGE(1, 1);

  const int rga = (lhi ^ ((l16 >> 1) & 3)) << 3;

  for (int t = 0; t < nt; ++t) {
    if (t < nt - 1) asm volatile("s_waitcnt vmcnt(4)" ::: "memory");
    else            asm volatile("s_waitcnt vmcnt(0)" ::: "memory");
    __builtin_amdgcn_s_barrier();
    if (t + 2 < nt) STAGE((t + 2) % 3, t + 2);

    const short* as_ = As[t % 3];
    const short* bs_ = Bs[t % 3];
    bf16x8 af[4], bfr[4];
#pragma unroll
    for (int mi = 0; mi < 4; ++mi)
      af[mi] = *reinterpret_cast<const bf16x8*>(
          &as_[(wr * 64 + mi * 16 + l16) * 32 + rga]);
#pragma unroll
    for (int ni = 0; ni < 4; ++ni)
      bfr[ni] = *reinterpret_cast<const bf16x8*>(
          &bs_[(wc * 64 + ni * 16 + l16) * 32 + rga]);
#pragma unroll
    for (int mi = 0; mi < 4; ++mi)
#pragma unroll
      for (int ni = 0; ni < 4; ++ni)
        acc[mi][ni] = __builtin_amdgcn_mfma_f32_16x16x32_bf16(
            af[mi], bfr[ni], acc[mi][ni], 0, 0, 0);
  }

#pragma unroll
  for (int mi = 0; mi < 4; ++mi)
#pragma unroll
    for (int ni = 0; ni < 4; ++ni) {
      int col = bn * 128 + wc * 64 + ni * 16 + l16;
#pragma unroll
      for (int r = 0; r < 4; ++r) {
        int row = bm * 128 + wr * 64 + mi * 16 + lhi * 4 + r;
        float v = acc[mi][ni][r];
        if (MODE == 0) {
          int b = row >> 11, s = row & 2047;
          int h = col / 192;
          int c = col - h * 192;
          int which = c >> 6, d = c & 63;
          int bh = b * 12 + h;
          if (which == 0) {
            qb[((bh << 11) + s) * 64 + d] = f2bf(v * 0.18033688f);
          } else {
            int pv = pidx[(b << 11) + s];
            if (pv & 1) {
              int sc = pv >> 1;
              if (which == 1) kb[((bh << 11) + sc) * 64 + d] = f2bf(v);
              else            vtb[((bh * 64 + d) << 11) + sc] = f2bf(v);
            }
          }
        } else {
          Cf[(int64_t)row * N + col] = v;
        }
      }
    }
}

// ---------- flash attention over COMPACTED K/V ----------
// R16 structure (best measured) + compaction: per batch only the ~len kept
// keys are visited (nt = ceil(len/64) tiles, ~17 vs 32). Bias is a register
// compare: key < len ? -12 (fixed-max shift) : -14400 (padding) -- no LDS
// bias table. Fixed-max softmax: p = exp2(z) directly.

__global__ __launch_bounds__(256, 2) void attn_kernel(
    const short* __restrict__ Qb, const short* __restrict__ Kb,
    const short* __restrict__ VTb, const int* __restrict__ lens,
    short* __restrict__ AO)
{
  __shared__ __align__(16) char Ks[3][8192];   // [64 keys][128B], XOR-8 swizzled
  __shared__ __align__(16) char Vs[3][8192];   // [64 d]   [128B], XOR-8 swizzled

  const int tid  = threadIdx.x;
  const int lane = tid & 63;
  const int wave = tid >> 6;
  const int l32  = lane & 31;
  const int hi   = lane >> 5;

  // XCD-pinned swizzle: all 16 q-tiles of one (b,h) on one XCD (K/V fit its L2)
  const int blk  = blockIdx.x;
  const int xcd  = blk & 7;
  const int slot = blk >> 3;            // 0..95
  const int bh   = xcd * 6 + (slot % 6);
  const int qt   = slot / 6;            // 0..15
  const int b    = bh / 12, h = bh - b * 12;
  const int qrow = qt * 128 + wave * 32 + l32;

  const short* Qp  = Qb + ((int64_t)bh * 2048 + qrow) * 64;
  const char*  KpB = (const char*)(Kb + (int64_t)bh * 2048 * 64);
  const char*  VpB = (const char*)(VTb + (int64_t)bh * 64 * 2048);

  const int len = lens[b];
  const int nt  = (len + 63) >> 6;

  // Q B-frags (col = own q, k = ks*16 + hi*8 + j)
  bf16x8 qf[4];
#pragma unroll
  for (int ks = 0; ks < 4; ++ks)
    qf[ks] = *reinterpret_cast<const bf16x8*>(Qp + ks * 16 + hi * 8);

  // staging geometry: thread covers LDS slot (row = s*32 + tid>>3, col16 = tid&7)
  const int str = tid >> 3;
  const int stc = tid & 7;
  const char* kSrc[2]; const char* vSrc[2]; int ldst[2];
#pragma unroll
  for (int s = 0; s < 2; ++s) {
    int r  = s * 32 + str;
    int cx = (stc ^ (r & 7)) << 4;
    kSrc[s] = KpB + (int64_t)r * 128 + cx;
    vSrc[s] = VpB + (int64_t)r * 4096 + cx;
    ldst[s] = s * 4096 + tid * 16;
  }

  auto STAGE = [&](int buf, int k0) {
#pragma unroll
    for (int s = 0; s < 2; ++s) {
      gload16(kSrc[s] + (int64_t)k0 * 128, &Ks[buf][ldst[s]]);
      gload16(vSrc[s] + (int64_t)k0 * 2,   &Vs[buf][ldst[s]]);
    }
  };

  const bf16x8 qb5 = frag_w0(hi == 0 ? 0x3f80u : 0u);  // B: 1.0 at k=0

  f32x16 o0 = {}, o1 = {};
  float lsum = 0.f;

  STAGE(0, 0);
  if (nt > 1) STAGE(1, 64);

  for (int kt = 0; kt < nt; ++kt) {
    const int cur = kt % 3;
    const int k0  = kt * 64;
    if (kt < nt - 1) asm volatile("s_waitcnt vmcnt(4)" ::: "memory");
    else             asm volatile("s_waitcnt vmcnt(0)" ::: "memory");
    __builtin_amdgcn_s_barrier();

    if (kt + 2 < nt) STAGE((kt + 2) % 3, (kt + 2) * 64);

    const char* kb_ = Ks[cur];
    const char* vb_ = Vs[cur];

    // ---- QK^T (+ bias-with-shift via extra MFMA), scores in log2 domain ----
    f32x16 st[2];
    __builtin_amdgcn_s_setprio(1);
#pragma unroll
    for (int kt2 = 0; kt2 < 2; ++kt2) {
      const int key = k0 + kt2 * 32 + l32;
      unsigned int bw = (key < len) ? 0xC140u : 0xC661u;  // -12 / -14400
      f32x16 z = {};
      z = __builtin_amdgcn_mfma_f32_32x32x16_bf16(
              frag_w0(hi == 0 ? bw : 0u), qb5, z, 0, 0, 0);
      const int r = kt2 * 32 + l32;
#pragma unroll
      for (int ks = 0; ks < 4; ++ks) {
        bf16x8 kf = *reinterpret_cast<const bf16x8*>(
            &kb_[r * 128 + (((ks * 2 + hi) ^ (r & 7)) << 4)]);
        z = __builtin_amdgcn_mfma_f32_32x32x16_bf16(kf, qf[ks], z, 0, 0, 0);
      }
      st[kt2] = z;
    }
    __builtin_amdgcn_s_setprio(0);

    // ---- fixed-max softmax: p = exp2(z) directly (shift already in bias) ----
    float psum = 0.f;
#pragma unroll
    for (int i = 0; i < 16; ++i) {
      float p = __builtin_amdgcn_exp2f(st[0][i]); st[0][i] = p; psum += p;
    }
#pragma unroll
    for (int i = 0; i < 16; ++i) {
      float p = __builtin_amdgcn_exp2f(st[1][i]); st[1][i] = p; psum += p;
    }
    lsum += psum;

    // ---- pack P into B-frags in-register (cvt_pk + permlane32_swap) ----
    bf16x8 pb[4];
#pragma unroll
    for (int w = 0; w < 4; ++w) {
      const f32x16& S = st[w >> 1];
      const int rb = (w & 1) * 8;
      unsigned int d01, d23, d45, d67;
      asm("v_cvt_pk_bf16_f32 %0, %1, %2" : "=v"(d01) : "v"(S[rb + 0]), "v"(S[rb + 1]));
      asm("v_cvt_pk_bf16_f32 %0, %1, %2" : "=v"(d23) : "v"(S[rb + 2]), "v"(S[rb + 3]));
      asm("v_cvt_pk_bf16_f32 %0, %1, %2" : "=v"(d45) : "v"(S[rb + 4]), "v"(S[rb + 5]));
      asm("v_cvt_pk_bf16_f32 %0, %1, %2" : "=v"(d67) : "v"(S[rb + 6]), "v"(S[rb + 7]));
      asm("v_permlane32_swap_b32 %0, %1" : "+v"(d01), "+v"(d45));
      asm("v_permlane32_swap_b32 %0, %1" : "+v"(d23), "+v"(d67));
      union { unsigned int u[4]; bf16x8 v; } t;
      t.u[0] = d01; t.u[1] = d23; t.u[2] = d45; t.u[3] = d67;
      pb[w] = t.v;
    }

    // ---- PV: O^T += V x P ----
    __builtin_amdgcn_s_setprio(1);
#pragma unroll
    for (int ks = 0; ks < 4; ++ks) {
      const int r0 = l32, r1 = 32 + l32;
      bf16x8 va0 = *reinterpret_cast<const bf16x8*>(
          &vb_[r0 * 128 + (((ks * 2 + hi) ^ (r0 & 7)) << 4)]);
      o0 = __builtin_amdgcn_mfma_f32_32x32x16_bf16(va0, pb[ks], o0, 0, 0, 0);
      bf16x8 va1 = *reinterpret_cast<const bf16x8*>(
          &vb_[r1 * 128 + (((ks * 2 + hi) ^ (r1 & 7)) << 4)]);
      o1 = __builtin_amdgcn_mfma_f32_32x32x16_bf16(va1, pb[ks], o1, 0, 0, 0);
    }
    __builtin_amdgcn_s_setprio(0);
  }

  // ---- epilogue: per-lane normalize, write own q-row ----
  float lrun = lsum + __shfl_xor(lsum, 32);
  float inv  = 1.0f / lrun;
  short* Orow = AO + ((int64_t)(b * 2048) + qrow) * 768 + h * 64;
#pragma unroll
  for (int dt = 0; dt < 2; ++dt) {
    const f32x16& O = dt ? o1 : o0;
#pragma unroll
    for (int rp = 0; rp < 8; ++rp) {
      int dbase = dt * 32 + (rp & 1) * 2 + (rp >> 1) * 8 + hi * 4;
      float a = O[2 * rp] * inv, bvl = O[2 * rp + 1] * inv;
      unsigned int wpk;
      asm("v_cvt_pk_bf16_f32 %0, %1, %2" : "=v"(wpk) : "v"(a), "v"(bvl));
      *reinterpret_cast<unsigned int*>(Orow + dbase) = wpk;
    }
  }
}

// ---------- launch ----------

extern "C" void kernel_launch(void* const* d_in, const int* in_sizes, int n_in,
                              void* d_out, int out_size, void* d_ws, size_t ws_size,
                              hipStream_t stream) {
  const float* x    = (const float*)d_in[0];
  const float* wqkv = (const float*)d_in[1];
  const float* wout = (const float*)d_in[2];
  const int*   mask = (const int*)d_in[3];
  float* out = (float*)d_out;

  char* ws = (char*)d_ws;
  short* Qb  = (short*)(ws + 0);          // 48*2048*64 bf16 = 12.58 MB
  short* Kb  = (short*)(ws + 12582912);   // compacted keys + zero tail
  short* VT  = (short*)(ws + 25165824);   // [bh][d][s'] compacted + zero tail
  short* Xbf = (short*)(ws + 37748736);   // x bf16; later reused as attn-out bf16
  short* Wq  = (short*)(ws + 50331648);
  short* Wo  = (short*)(ws + 53870592);
  int*   Pidx = (int*)(ws + 55050240);    // 4*2048 ints = 32 KB
  int*   Lens = (int*)(ws + 55083008);    // 4 ints

  mask_scan<<<4, 256, 0, stream>>>(mask, Pidx, Lens, Kb, VT);

  cvt_all<<<8448, 256, 0, stream>>>(x, Xbf, wqkv, Wq, wout, Wo);

  gemm_bt<0><<<64 * 18, 256, 0, stream>>>(Xbf, Wq, nullptr, Qb, Kb, VT, Pidx,
                                          8192, 2304, 768);

  attn_kernel<<<48 * 16, 256, 0, stream>>>(Qb, Kb, VT, Lens, Xbf);

  gemm_bt<1><<<64 * 6, 256, 0, stream>>>(Xbf, Wo, out, nullptr, nullptr, nullptr,
                                         Pidx, 8192, 768, 768);
}

// Round 19
// 152.870 us; speedup vs baseline: 1.0171x; 1.0171x over previous
//
#include <hip/hip_runtime.h>
#include <hip/hip_bf16.h>
#include <stdint.h>

typedef __attribute__((ext_vector_type(4)))  float  f32x4;
typedef __attribute__((ext_vector_type(16))) float  f32x16;
typedef __attribute__((ext_vector_type(8)))  __bf16 bf16x8;
typedef __attribute__((ext_vector_type(4)))  float  float4_t;
typedef __attribute__((ext_vector_type(4)))  int    int4_t;

// ---------- helpers ----------

__device__ __forceinline__ short f2bf(float f) {
  uint32_t u = __builtin_bit_cast(uint32_t, f);
  return (short)((u + 0x7FFFu + ((u >> 16) & 1u)) >> 16);
}

__device__ __forceinline__ void gload16(const void* g, void* l) {
  __builtin_amdgcn_global_load_lds(
      (const __attribute__((address_space(1))) void*)g,
      (__attribute__((address_space(3))) void*)l, 16, 0, 0);
}

__device__ __forceinline__ bf16x8 frag_w0(unsigned int w0) {
  union { unsigned int u[4]; bf16x8 v; } t;
  t.u[0] = w0; t.u[1] = 0; t.u[2] = 0; t.u[3] = 0;
  return t.v;
}

// ---------- fused convert + mask scan (one dispatch) ----------
// blocks [0,8448): fp32->bf16 convert of x / w_qkv / w_out (float4 units:
// 1572864 / 442368 / 147456). blocks [8448,8452): per-batch mask prefix scan
// -> pidx[s] = (cidx<<1)|keep, lens[b]; zero compacted K tail rows & VT tail
// cols so padding keys score bias(-14400) -> p = 0 exactly.

__global__ void cvt_scan(const float* __restrict__ x,   short* __restrict__ xo,
                         const float* __restrict__ w1,  short* __restrict__ w1o,
                         const float* __restrict__ w2,  short* __restrict__ w2o,
                         const int* __restrict__ mask, int* __restrict__ pidx,
                         int* __restrict__ lens,
                         short* __restrict__ kb, short* __restrict__ vtb) {
  const int tid = threadIdx.x;
  if (blockIdx.x >= 8448) {
    const int b = blockIdx.x - 8448;
    const int lane = tid & 63, wv = tid >> 6;
    __shared__ int wtot[4];
    const int* mb = mask + (b << 11);
    int4_t a = reinterpret_cast<const int4_t*>(mb)[tid * 2];
    int4_t c = reinterpret_cast<const int4_t*>(mb)[tid * 2 + 1];
    int m[8] = {a[0] ? 1 : 0, a[1] ? 1 : 0, a[2] ? 1 : 0, a[3] ? 1 : 0,
                c[0] ? 1 : 0, c[1] ? 1 : 0, c[2] ? 1 : 0, c[3] ? 1 : 0};
    int tsum = 0;
#pragma unroll
    for (int j = 0; j < 8; ++j) tsum += m[j];
    int inc = tsum;
#pragma unroll
    for (int d = 1; d < 64; d <<= 1) {
      int t = __shfl_up(inc, d);
      if (lane >= d) inc += t;
    }
    if (lane == 63) wtot[wv] = inc;
    __syncthreads();
    int woff = 0;
#pragma unroll
    for (int w = 0; w < 3; ++w) if (w < wv) woff += wtot[w];
    int run = woff + inc - tsum;
#pragma unroll
    for (int j = 0; j < 8; ++j) {
      pidx[(b << 11) + tid * 8 + j] = (run << 1) | m[j];
      run += m[j];
    }
    const int total = wtot[0] + wtot[1] + wtot[2] + wtot[3];
    if (tid == 0) lens[b] = total;
    const int pad  = (total + 63) & ~63;
    const int tail = pad - total;
    if (tail == 0) return;
    for (int h = 0; h < 12; ++h) {
      uint64_t* kbase = reinterpret_cast<uint64_t*>(
          kb + ((((int64_t)(b * 12 + h)) << 11) + total) * 64);
      for (int i = tid; i < tail * 8; i += 256) kbase[i] = 0;
      short* vbase = vtb + (((int64_t)(b * 12 + h)) * 64 << 11);
      for (int i = tid; i < 64 * tail; i += 256) {
        int d = i / tail, s = total + i % tail;
        vbase[(d << 11) + s] = 0;
      }
    }
    return;
  }
  int i = blockIdx.x * 256 + tid;
  const float* src; short* dst;
  if (i < 1572864)      { src = x;  dst = xo; }
  else if (i < 2015232) { src = w1; dst = w1o; i -= 1572864; }
  else if (i < 2162688) { src = w2; dst = w2o; i -= 2015232; }
  else return;
  float4_t v = reinterpret_cast<const float4_t*>(src)[i];
  union { short s[4]; uint64_t u; } o;
  o.s[0] = f2bf(v[0]); o.s[1] = f2bf(v[1]);
  o.s[2] = f2bf(v[2]); o.s[3] = f2bf(v[3]);
  reinterpret_cast<uint64_t*>(dst)[i] = o.u;
}

// ---------- 128x128 bf16 GEMM, C = A[M,K] * W[N,K]^T ----------
// R19: BK=32, FOUR-buffer LDS pipeline (64 KB), loads THREE tiles ahead,
// tiered counted vmcnt (8 steady / 4 / 0 tail) -- lookahead ~450+ cyc to
// cover L2-miss latency that 2-deep didn't (gemm stuck ~75-78 us across 4
// structures, MfmaUtil 14%, all pipes idle). 2-way-free XOR column swizzle
// (bank conflicts measured 0). XCD-chunked block swizzle.
// MODE 0: QKV scatter with per-batch K/V compaction via pidx (loads hoisted);
// MODE 1: plain fp32 C.

template<int MODE>
__global__ __launch_bounds__(256) void gemm_bt(
    const short* __restrict__ A, const short* __restrict__ Bw,
    float* __restrict__ Cf,
    short* __restrict__ qb, short* __restrict__ kb, short* __restrict__ vtb,
    const int* __restrict__ pidx,
    int M, int N, int K)
{
  __shared__ __align__(16) short As[4][128 * 32];
  __shared__ __align__(16) short Bs[4][128 * 32];
  const int tid  = threadIdx.x;
  const int lane = tid & 63;
  const int wave = tid >> 6;
  const int ntn  = N >> 7;
  const int cpx  = gridDim.x >> 3;
  const int nid  = (blockIdx.x & 7) * cpx + (blockIdx.x >> 3);
  const int bm   = nid / ntn;
  const int bn   = nid % ntn;
  const int wr   = wave >> 1, wc = wave & 1;
  const int l16  = lane & 15, lhi = lane >> 4;

  f32x4 acc[4][4] = {};

  const int srow = lane >> 2;
  const int sg   = lane & 3;
  const int sgx  = (sg ^ ((srow >> 1) & 3)) * 8;
  const short* aG = A  + (int64_t)(bm * 128) * K;
  const short* bG = Bw + (int64_t)(bn * 128) * K;
  const int nt = K >> 5;

  auto STAGE = [&](int buf, int t) {
    const int k0 = t * 32;
#pragma unroll
    for (int i = 0; i < 2; ++i) {
      int rr = wave * 32 + i * 16 + srow;
      gload16(aG + (int64_t)rr * K + k0 + sgx,
              &As[buf][(wave * 32 + i * 16) * 32 + lane * 8]);
      gload16(bG + (int64_t)rr * K + k0 + sgx,
              &Bs[buf][(wave * 32 + i * 16) * 32 + lane * 8]);
    }
  };

  STAGE(0, 0);
  STAGE(1, 1);
  STAGE(2, 2);

  const int rga = (lhi ^ ((l16 >> 1) & 3)) << 3;

  for (int t = 0; t < nt; ++t) {
    // outstanding at top: 4 loads per staged tile, tiles t..min(t+2,nt-1)
    if (t + 3 <= nt)      asm volatile("s_waitcnt vmcnt(8)" ::: "memory");
    else if (t + 2 == nt) asm volatile("s_waitcnt vmcnt(4)" ::: "memory");
    else                  asm volatile("s_waitcnt vmcnt(0)" ::: "memory");
    __builtin_amdgcn_s_barrier();
    if (t + 3 < nt) STAGE((t + 3) & 3, t + 3);

    const short* as_ = As[t & 3];
    const short* bs_ = Bs[t & 3];
    bf16x8 af[4], bfr[4];
#pragma unroll
    for (int mi = 0; mi < 4; ++mi)
      af[mi] = *reinterpret_cast<const bf16x8*>(
          &as_[(wr * 64 + mi * 16 + l16) * 32 + rga]);
#pragma unroll
    for (int ni = 0; ni < 4; ++ni)
      bfr[ni] = *reinterpret_cast<const bf16x8*>(
          &bs_[(wc * 64 + ni * 16 + l16) * 32 + rga]);
#pragma unroll
    for (int mi = 0; mi < 4; ++mi)
#pragma unroll
      for (int ni = 0; ni < 4; ++ni)
        acc[mi][ni] = __builtin_amdgcn_mfma_f32_16x16x32_bf16(
            af[mi], bfr[ni], acc[mi][ni], 0, 0, 0);
  }

  // hoisted pidx loads (lane-uniform per quarter-wave, constant-indexed)
  int pv16[16];
  if (MODE == 0) {
#pragma unroll
    for (int mi = 0; mi < 4; ++mi)
#pragma unroll
      for (int r = 0; r < 4; ++r) {
        int row = bm * 128 + wr * 64 + mi * 16 + lhi * 4 + r;
        pv16[mi * 4 + r] = pidx[((row >> 11) << 11) + (row & 2047)];
      }
  }

#pragma unroll
  for (int mi = 0; mi < 4; ++mi)
#pragma unroll
    for (int ni = 0; ni < 4; ++ni) {
      int col = bn * 128 + wc * 64 + ni * 16 + l16;
#pragma unroll
      for (int r = 0; r < 4; ++r) {
        int row = bm * 128 + wr * 64 + mi * 16 + lhi * 4 + r;
        float v = acc[mi][ni][r];
        if (MODE == 0) {
          int b = row >> 11, s = row & 2047;
          int h = col / 192;
          int c = col - h * 192;
          int which = c >> 6, d = c & 63;
          int bh = b * 12 + h;
          if (which == 0) {
            qb[((bh << 11) + s) * 64 + d] = f2bf(v * 0.18033688f);
          } else {
            int pv = pv16[mi * 4 + r];
            if (pv & 1) {
              int sc = pv >> 1;
              if (which == 1) kb[((bh << 11) + sc) * 64 + d] = f2bf(v);
              else            vtb[((bh * 64 + d) << 11) + sc] = f2bf(v);
            }
          }
        } else {
          Cf[(int64_t)row * N + col] = v;
        }
      }
    }
}

// ---------- flash attention over COMPACTED K/V (R18, unchanged) ----------
// nt = ceil(len/64) tiles (~16 vs 32). Bias register compare: key < len ?
// -12 (fixed-max shift) : -14400. Fixed-max softmax: p = exp2(z) directly.

__global__ __launch_bounds__(256, 2) void attn_kernel(
    const short* __restrict__ Qb, const short* __restrict__ Kb,
    const short* __restrict__ VTb, const int* __restrict__ lens,
    short* __restrict__ AO)
{
  __shared__ __align__(16) char Ks[3][8192];   // [64 keys][128B], XOR-8 swizzled
  __shared__ __align__(16) char Vs[3][8192];   // [64 d]   [128B], XOR-8 swizzled

  const int tid  = threadIdx.x;
  const int lane = tid & 63;
  const int wave = tid >> 6;
  const int l32  = lane & 31;
  const int hi   = lane >> 5;

  const int blk  = blockIdx.x;
  const int xcd  = blk & 7;
  const int slot = blk >> 3;            // 0..95
  const int bh   = xcd * 6 + (slot % 6);
  const int qt   = slot / 6;            // 0..15
  const int b    = bh / 12, h = bh - b * 12;
  const int qrow = qt * 128 + wave * 32 + l32;

  const short* Qp  = Qb + ((int64_t)bh * 2048 + qrow) * 64;
  const char*  KpB = (const char*)(Kb + (int64_t)bh * 2048 * 64);
  const char*  VpB = (const char*)(VTb + (int64_t)bh * 64 * 2048);

  const int len = lens[b];
  const int nt  = (len + 63) >> 6;

  bf16x8 qf[4];
#pragma unroll
  for (int ks = 0; ks < 4; ++ks)
    qf[ks] = *reinterpret_cast<const bf16x8*>(Qp + ks * 16 + hi * 8);

  const int str = tid >> 3;
  const int stc = tid & 7;
  const char* kSrc[2]; const char* vSrc[2]; int ldst[2];
#pragma unroll
  for (int s = 0; s < 2; ++s) {
    int r  = s * 32 + str;
    int cx = (stc ^ (r & 7)) << 4;
    kSrc[s] = KpB + (int64_t)r * 128 + cx;
    vSrc[s] = VpB + (int64_t)r * 4096 + cx;
    ldst[s] = s * 4096 + tid * 16;
  }

  auto STAGE = [&](int buf, int k0) {
#pragma unroll
    for (int s = 0; s < 2; ++s) {
      gload16(kSrc[s] + (int64_t)k0 * 128, &Ks[buf][ldst[s]]);
      gload16(vSrc[s] + (int64_t)k0 * 2,   &Vs[buf][ldst[s]]);
    }
  };

  const bf16x8 qb5 = frag_w0(hi == 0 ? 0x3f80u : 0u);  // B: 1.0 at k=0

  f32x16 o0 = {}, o1 = {};
  float lsum = 0.f;

  STAGE(0, 0);
  if (nt > 1) STAGE(1, 64);

  for (int kt = 0; kt < nt; ++kt) {
    const int cur = kt % 3;
    const int k0  = kt * 64;
    if (kt < nt - 1) asm volatile("s_waitcnt vmcnt(4)" ::: "memory");
    else             asm volatile("s_waitcnt vmcnt(0)" ::: "memory");
    __builtin_amdgcn_s_barrier();

    if (kt + 2 < nt) STAGE((kt + 2) % 3, (kt + 2) * 64);

    const char* kb_ = Ks[cur];
    const char* vb_ = Vs[cur];

    f32x16 st[2];
    __builtin_amdgcn_s_setprio(1);
#pragma unroll
    for (int kt2 = 0; kt2 < 2; ++kt2) {
      const int key = k0 + kt2 * 32 + l32;
      unsigned int bw = (key < len) ? 0xC140u : 0xC661u;  // -12 / -14400
      f32x16 z = {};
      z = __builtin_amdgcn_mfma_f32_32x32x16_bf16(
              frag_w0(hi == 0 ? bw : 0u), qb5, z, 0, 0, 0);
      const int r = kt2 * 32 + l32;
#pragma unroll
      for (int ks = 0; ks < 4; ++ks) {
        bf16x8 kf = *reinterpret_cast<const bf16x8*>(
            &kb_[r * 128 + (((ks * 2 + hi) ^ (r & 7)) << 4)]);
        z = __builtin_amdgcn_mfma_f32_32x32x16_bf16(kf, qf[ks], z, 0, 0, 0);
      }
      st[kt2] = z;
    }
    __builtin_amdgcn_s_setprio(0);

    float psum = 0.f;
#pragma unroll
    for (int i = 0; i < 16; ++i) {
      float p = __builtin_amdgcn_exp2f(st[0][i]); st[0][i] = p; psum += p;
    }
#pragma unroll
    for (int i = 0; i < 16; ++i) {
      float p = __builtin_amdgcn_exp2f(st[1][i]); st[1][i] = p; psum += p;
    }
    lsum += psum;

    bf16x8 pb[4];
#pragma unroll
    for (int w = 0; w < 4; ++w) {
      const f32x16& S = st[w >> 1];
      const int rb = (w & 1) * 8;
      unsigned int d01, d23, d45, d67;
      asm("v_cvt_pk_bf16_f32 %0, %1, %2" : "=v"(d01) : "v"(S[rb + 0]), "v"(S[rb + 1]));
      asm("v_cvt_pk_bf16_f32 %0, %1, %2" : "=v"(d23) : "v"(S[rb + 2]), "v"(S[rb + 3]));
      asm("v_cvt_pk_bf16_f32 %0, %1, %2" : "=v"(d45) : "v"(S[rb + 4]), "v"(S[rb + 5]));
      asm("v_cvt_pk_bf16_f32 %0, %1, %2" : "=v"(d67) : "v"(S[rb + 6]), "v"(S[rb + 7]));
      asm("v_permlane32_swap_b32 %0, %1" : "+v"(d01), "+v"(d45));
      asm("v_permlane32_swap_b32 %0, %1" : "+v"(d23), "+v"(d67));
      union { unsigned int u[4]; bf16x8 v; } t;
      t.u[0] = d01; t.u[1] = d23; t.u[2] = d45; t.u[3] = d67;
      pb[w] = t.v;
    }

    __builtin_amdgcn_s_setprio(1);
#pragma unroll
    for (int ks = 0; ks < 4; ++ks) {
      const int r0 = l32, r1 = 32 + l32;
      bf16x8 va0 = *reinterpret_cast<const bf16x8*>(
          &vb_[r0 * 128 + (((ks * 2 + hi) ^ (r0 & 7)) << 4)]);
      o0 = __builtin_amdgcn_mfma_f32_32x32x16_bf16(va0, pb[ks], o0, 0, 0, 0);
      bf16x8 va1 = *reinterpret_cast<const bf16x8*>(
          &vb_[r1 * 128 + (((ks * 2 + hi) ^ (r1 & 7)) << 4)]);
      o1 = __builtin_amdgcn_mfma_f32_32x32x16_bf16(va1, pb[ks], o1, 0, 0, 0);
    }
    __builtin_amdgcn_s_setprio(0);
  }

  float lrun = lsum + __shfl_xor(lsum, 32);
  float inv  = 1.0f / lrun;
  short* Orow = AO + ((int64_t)(b * 2048) + qrow) * 768 + h * 64;
#pragma unroll
  for (int dt = 0; dt < 2; ++dt) {
    const f32x16& O = dt ? o1 : o0;
#pragma unroll
    for (int rp = 0; rp < 8; ++rp) {
      int dbase = dt * 32 + (rp & 1) * 2 + (rp >> 1) * 8 + hi * 4;
      float a = O[2 * rp] * inv, bvl = O[2 * rp + 1] * inv;
      unsigned int wpk;
      asm("v_cvt_pk_bf16_f32 %0, %1, %2" : "=v"(wpk) : "v"(a), "v"(bvl));
      *reinterpret_cast<unsigned int*>(Orow + dbase) = wpk;
    }
  }
}

// ---------- launch ----------

extern "C" void kernel_launch(void* const* d_in, const int* in_sizes, int n_in,
                              void* d_out, int out_size, void* d_ws, size_t ws_size,
                              hipStream_t stream) {
  const float* x    = (const float*)d_in[0];
  const float* wqkv = (const float*)d_in[1];
  const float* wout = (const float*)d_in[2];
  const int*   mask = (const int*)d_in[3];
  float* out = (float*)d_out;

  char* ws = (char*)d_ws;
  short* Qb  = (short*)(ws + 0);          // 48*2048*64 bf16 = 12.58 MB
  short* Kb  = (short*)(ws + 12582912);   // compacted keys + zero tail
  short* VT  = (short*)(ws + 25165824);   // [bh][d][s'] compacted + zero tail
  short* Xbf = (short*)(ws + 37748736);   // x bf16; later reused as attn-out bf16
  short* Wq  = (short*)(ws + 50331648);
  short* Wo  = (short*)(ws + 53870592);
  int*   Pidx = (int*)(ws + 55050240);    // 4*2048 ints = 32 KB
  int*   Lens = (int*)(ws + 55083008);    // 4 ints

  cvt_scan<<<8452, 256, 0, stream>>>(x, Xbf, wqkv, Wq, wout, Wo,
                                     mask, Pidx, Lens, Kb, VT);

  gemm_bt<0><<<64 * 18, 256, 0, stream>>>(Xbf, Wq, nullptr, Qb, Kb, VT, Pidx,
                                          8192, 2304, 768);

  attn_kernel<<<48 * 16, 256, 0, stream>>>(Qb, Kb, VT, Lens, Xbf);

  gemm_bt<1><<<64 * 6, 256, 0, stream>>>(Xbf, Wo, out, nullptr, nullptr, nullptr,
                                         Pidx, 8192, 768, 768);
}

// Round 20
// 136.062 us; speedup vs baseline: 1.1428x; 1.1235x over previous
//
#include <hip/hip_runtime.h>
#include <hip/hip_bf16.h>
#include <stdint.h>

typedef __attribute__((ext_vector_type(4)))  float  f32x4;
typedef __attribute__((ext_vector_type(16))) float  f32x16;
typedef __attribute__((ext_vector_type(8)))  __bf16 bf16x8;
typedef __attribute__((ext_vector_type(4)))  float  float4_t;
typedef __attribute__((ext_vector_type(4)))  int    int4_t;

// ---------- helpers ----------

__device__ __forceinline__ short f2bf(float f) {
  uint32_t u = __builtin_bit_cast(uint32_t, f);
  return (short)((u + 0x7FFFu + ((u >> 16) & 1u)) >> 16);
}

__device__ __forceinline__ void gload16(const void* g, void* l) {
  __builtin_amdgcn_global_load_lds(
      (const __attribute__((address_space(1))) void*)g,
      (__attribute__((address_space(3))) void*)l, 16, 0, 0);
}

__device__ __forceinline__ bf16x8 frag_w0(unsigned int w0) {
  union { unsigned int u[4]; bf16x8 v; } t;
  t.u[0] = w0; t.u[1] = 0; t.u[2] = 0; t.u[3] = 0;
  return t.v;
}

// ---------- fused convert + mask scan (one dispatch) ----------
// blocks [0,8448): fp32->bf16 convert of x / w_qkv / w_out.
// blocks [8448,8452): per-batch mask prefix scan -> pidx, lens; zero
// compacted K tail rows & VT tail cols (padding keys -> p = 0 exactly).

__global__ void cvt_scan(const float* __restrict__ x,   short* __restrict__ xo,
                         const float* __restrict__ w1,  short* __restrict__ w1o,
                         const float* __restrict__ w2,  short* __restrict__ w2o,
                         const int* __restrict__ mask, int* __restrict__ pidx,
                         int* __restrict__ lens,
                         short* __restrict__ kb, short* __restrict__ vtb) {
  const int tid = threadIdx.x;
  if (blockIdx.x >= 8448) {
    const int b = blockIdx.x - 8448;
    const int lane = tid & 63, wv = tid >> 6;
    __shared__ int wtot[4];
    const int* mb = mask + (b << 11);
    int4_t a = reinterpret_cast<const int4_t*>(mb)[tid * 2];
    int4_t c = reinterpret_cast<const int4_t*>(mb)[tid * 2 + 1];
    int m[8] = {a[0] ? 1 : 0, a[1] ? 1 : 0, a[2] ? 1 : 0, a[3] ? 1 : 0,
                c[0] ? 1 : 0, c[1] ? 1 : 0, c[2] ? 1 : 0, c[3] ? 1 : 0};
    int tsum = 0;
#pragma unroll
    for (int j = 0; j < 8; ++j) tsum += m[j];
    int inc = tsum;
#pragma unroll
    for (int d = 1; d < 64; d <<= 1) {
      int t = __shfl_up(inc, d);
      if (lane >= d) inc += t;
    }
    if (lane == 63) wtot[wv] = inc;
    __syncthreads();
    int woff = 0;
#pragma unroll
    for (int w = 0; w < 3; ++w) if (w < wv) woff += wtot[w];
    int run = woff + inc - tsum;
#pragma unroll
    for (int j = 0; j < 8; ++j) {
      pidx[(b << 11) + tid * 8 + j] = (run << 1) | m[j];
      run += m[j];
    }
    const int total = wtot[0] + wtot[1] + wtot[2] + wtot[3];
    if (tid == 0) lens[b] = total;
    const int pad  = (total + 63) & ~63;
    const int tail = pad - total;
    if (tail == 0) return;
    for (int h = 0; h < 12; ++h) {
      uint64_t* kbase = reinterpret_cast<uint64_t*>(
          kb + ((((int64_t)(b * 12 + h)) << 11) + total) * 64);
      for (int i = tid; i < tail * 8; i += 256) kbase[i] = 0;
      short* vbase = vtb + (((int64_t)(b * 12 + h)) * 64 << 11);
      for (int i = tid; i < 64 * tail; i += 256) {
        int d = i / tail, s = total + i % tail;
        vbase[(d << 11) + s] = 0;
      }
    }
    return;
  }
  int i = blockIdx.x * 256 + tid;
  const float* src; short* dst;
  if (i < 1572864)      { src = x;  dst = xo; }
  else if (i < 2015232) { src = w1; dst = w1o; i -= 1572864; }
  else if (i < 2162688) { src = w2; dst = w2o; i -= 2015232; }
  else return;
  float4_t v = reinterpret_cast<const float4_t*>(src)[i];
  union { short s[4]; uint64_t u; } o;
  o.s[0] = f2bf(v[0]); o.s[1] = f2bf(v[1]);
  o.s[2] = f2bf(v[2]); o.s[3] = f2bf(v[3]);
  reinterpret_cast<uint64_t*>(dst)[i] = o.u;
}

// ---------- 128x128 bf16 GEMM, C = A[M,K] * W[N,K]^T ----------
// R20: EXACT R16 pipeline restored (the ledger's fastest: ~50 us for gemm0):
// BK=32, 3-buffer LDS (48 KB -> 3 blocks/CU), counted vmcnt(4), loads 2
// tiles ahead, 2-way-free XOR column swizzle (bank conflicts measured 0),
// XCD-chunked block swizzle. R18's in-loop pidx loads (48 serial dependent
// L2 loads/thread, +28 us) replaced by R19's hoisted pv16 (16 parallel).
// MODE 0: QKV scatter with per-batch K/V compaction; MODE 1: plain fp32 C.

template<int MODE>
__global__ __launch_bounds__(256) void gemm_bt(
    const short* __restrict__ A, const short* __restrict__ Bw,
    float* __restrict__ Cf,
    short* __restrict__ qb, short* __restrict__ kb, short* __restrict__ vtb,
    const int* __restrict__ pidx,
    int M, int N, int K)
{
  __shared__ __align__(16) short As[3][128 * 32];
  __shared__ __align__(16) short Bs[3][128 * 32];
  const int tid  = threadIdx.x;
  const int lane = tid & 63;
  const int wave = tid >> 6;
  const int ntn  = N >> 7;
  const int cpx  = gridDim.x >> 3;
  const int nid  = (blockIdx.x & 7) * cpx + (blockIdx.x >> 3);
  const int bm   = nid / ntn;
  const int bn   = nid % ntn;
  const int wr   = wave >> 1, wc = wave & 1;
  const int l16  = lane & 15, lhi = lane >> 4;

  f32x4 acc[4][4] = {};

  const int srow = lane >> 2;
  const int sg   = lane & 3;
  const int sgx  = (sg ^ ((srow >> 1) & 3)) * 8;
  const short* aG = A  + (int64_t)(bm * 128) * K;
  const short* bG = Bw + (int64_t)(bn * 128) * K;
  const int nt = K >> 5;

  auto STAGE = [&](int buf, int t) {
    const int k0 = t * 32;
#pragma unroll
    for (int i = 0; i < 2; ++i) {
      int rr = wave * 32 + i * 16 + srow;
      gload16(aG + (int64_t)rr * K + k0 + sgx,
              &As[buf][(wave * 32 + i * 16) * 32 + lane * 8]);
      gload16(bG + (int64_t)rr * K + k0 + sgx,
              &Bs[buf][(wave * 32 + i * 16) * 32 + lane * 8]);
    }
  };

  STAGE(0, 0);
  STAGE(1, 1);

  const int rga = (lhi ^ ((l16 >> 1) & 3)) << 3;

  for (int t = 0; t < nt; ++t) {
    if (t < nt - 1) asm volatile("s_waitcnt vmcnt(4)" ::: "memory");
    else            asm volatile("s_waitcnt vmcnt(0)" ::: "memory");
    __builtin_amdgcn_s_barrier();
    if (t + 2 < nt) STAGE((t + 2) % 3, t + 2);

    const short* as_ = As[t % 3];
    const short* bs_ = Bs[t % 3];
    bf16x8 af[4], bfr[4];
#pragma unroll
    for (int mi = 0; mi < 4; ++mi)
      af[mi] = *reinterpret_cast<const bf16x8*>(
          &as_[(wr * 64 + mi * 16 + l16) * 32 + rga]);
#pragma unroll
    for (int ni = 0; ni < 4; ++ni)
      bfr[ni] = *reinterpret_cast<const bf16x8*>(
          &bs_[(wc * 64 + ni * 16 + l16) * 32 + rga]);
#pragma unroll
    for (int mi = 0; mi < 4; ++mi)
#pragma unroll
      for (int ni = 0; ni < 4; ++ni)
        acc[mi][ni] = __builtin_amdgcn_mfma_f32_16x16x32_bf16(
            af[mi], bfr[ni], acc[mi][ni], 0, 0, 0);
  }

  // hoisted pidx loads: 16 independent L2 loads, issued together (one
  // latency), instead of R18's 48 serial dependent in-loop loads.
  int pv16[16];
  if (MODE == 0) {
#pragma unroll
    for (int mi = 0; mi < 4; ++mi)
#pragma unroll
      for (int r = 0; r < 4; ++r) {
        int row = bm * 128 + wr * 64 + mi * 16 + lhi * 4 + r;
        pv16[mi * 4 + r] = pidx[((row >> 11) << 11) + (row & 2047)];
      }
  }

#pragma unroll
  for (int mi = 0; mi < 4; ++mi)
#pragma unroll
    for (int ni = 0; ni < 4; ++ni) {
      int col = bn * 128 + wc * 64 + ni * 16 + l16;
#pragma unroll
      for (int r = 0; r < 4; ++r) {
        int row = bm * 128 + wr * 64 + mi * 16 + lhi * 4 + r;
        float v = acc[mi][ni][r];
        if (MODE == 0) {
          int b = row >> 11, s = row & 2047;
          int h = col / 192;
          int c = col - h * 192;
          int which = c >> 6, d = c & 63;
          int bh = b * 12 + h;
          if (which == 0) {
            qb[((bh << 11) + s) * 64 + d] = f2bf(v * 0.18033688f);
          } else {
            int pv = pv16[mi * 4 + r];
            if (pv & 1) {
              int sc = pv >> 1;
              if (which == 1) kb[((bh << 11) + sc) * 64 + d] = f2bf(v);
              else            vtb[((bh * 64 + d) << 11) + sc] = f2bf(v);
            }
          }
        } else {
          Cf[(int64_t)row * N + col] = v;
        }
      }
    }
}

// ---------- flash attention over COMPACTED K/V (unchanged) ----------
// nt = ceil(len/64) tiles (~16 vs 32). Bias register compare: key < len ?
// -12 (fixed-max shift) : -14400. Fixed-max softmax: p = exp2(z) directly.

__global__ __launch_bounds__(256, 2) void attn_kernel(
    const short* __restrict__ Qb, const short* __restrict__ Kb,
    const short* __restrict__ VTb, const int* __restrict__ lens,
    short* __restrict__ AO)
{
  __shared__ __align__(16) char Ks[3][8192];   // [64 keys][128B], XOR-8 swizzled
  __shared__ __align__(16) char Vs[3][8192];   // [64 d]   [128B], XOR-8 swizzled

  const int tid  = threadIdx.x;
  const int lane = tid & 63;
  const int wave = tid >> 6;
  const int l32  = lane & 31;
  const int hi   = lane >> 5;

  const int blk  = blockIdx.x;
  const int xcd  = blk & 7;
  const int slot = blk >> 3;            // 0..95
  const int bh   = xcd * 6 + (slot % 6);
  const int qt   = slot / 6;            // 0..15
  const int b    = bh / 12, h = bh - b * 12;
  const int qrow = qt * 128 + wave * 32 + l32;

  const short* Qp  = Qb + ((int64_t)bh * 2048 + qrow) * 64;
  const char*  KpB = (const char*)(Kb + (int64_t)bh * 2048 * 64);
  const char*  VpB = (const char*)(VTb + (int64_t)bh * 64 * 2048);

  const int len = lens[b];
  const int nt  = (len + 63) >> 6;

  bf16x8 qf[4];
#pragma unroll
  for (int ks = 0; ks < 4; ++ks)
    qf[ks] = *reinterpret_cast<const bf16x8*>(Qp + ks * 16 + hi * 8);

  const int str = tid >> 3;
  const int stc = tid & 7;
  const char* kSrc[2]; const char* vSrc[2]; int ldst[2];
#pragma unroll
  for (int s = 0; s < 2; ++s) {
    int r  = s * 32 + str;
    int cx = (stc ^ (r & 7)) << 4;
    kSrc[s] = KpB + (int64_t)r * 128 + cx;
    vSrc[s] = VpB + (int64_t)r * 4096 + cx;
    ldst[s] = s * 4096 + tid * 16;
  }

  auto STAGE = [&](int buf, int k0) {
#pragma unroll
    for (int s = 0; s < 2; ++s) {
      gload16(kSrc[s] + (int64_t)k0 * 128, &Ks[buf][ldst[s]]);
      gload16(vSrc[s] + (int64_t)k0 * 2,   &Vs[buf][ldst[s]]);
    }
  };

  const bf16x8 qb5 = frag_w0(hi == 0 ? 0x3f80u : 0u);  // B: 1.0 at k=0

  f32x16 o0 = {}, o1 = {};
  float lsum = 0.f;

  STAGE(0, 0);
  if (nt > 1) STAGE(1, 64);

  for (int kt = 0; kt < nt; ++kt) {
    const int cur = kt % 3;
    const int k0  = kt * 64;
    if (kt < nt - 1) asm volatile("s_waitcnt vmcnt(4)" ::: "memory");
    else             asm volatile("s_waitcnt vmcnt(0)" ::: "memory");
    __builtin_amdgcn_s_barrier();

    if (kt + 2 < nt) STAGE((kt + 2) % 3, (kt + 2) * 64);

    const char* kb_ = Ks[cur];
    const char* vb_ = Vs[cur];

    f32x16 st[2];
    __builtin_amdgcn_s_setprio(1);
#pragma unroll
    for (int kt2 = 0; kt2 < 2; ++kt2) {
      const int key = k0 + kt2 * 32 + l32;
      unsigned int bw = (key < len) ? 0xC140u : 0xC661u;  // -12 / -14400
      f32x16 z = {};
      z = __builtin_amdgcn_mfma_f32_32x32x16_bf16(
              frag_w0(hi == 0 ? bw : 0u), qb5, z, 0, 0, 0);
      const int r = kt2 * 32 + l32;
#pragma unroll
      for (int ks = 0; ks < 4; ++ks) {
        bf16x8 kf = *reinterpret_cast<const bf16x8*>(
            &kb_[r * 128 + (((ks * 2 + hi) ^ (r & 7)) << 4)]);
        z = __builtin_amdgcn_mfma_f32_32x32x16_bf16(kf, qf[ks], z, 0, 0, 0);
      }
      st[kt2] = z;
    }
    __builtin_amdgcn_s_setprio(0);

    float psum = 0.f;
#pragma unroll
    for (int i = 0; i < 16; ++i) {
      float p = __builtin_amdgcn_exp2f(st[0][i]); st[0][i] = p; psum += p;
    }
#pragma unroll
    for (int i = 0; i < 16; ++i) {
      float p = __builtin_amdgcn_exp2f(st[1][i]); st[1][i] = p; psum += p;
    }
    lsum += psum;

    bf16x8 pb[4];
#pragma unroll
    for (int w = 0; w < 4; ++w) {
      const f32x16& S = st[w >> 1];
      const int rb = (w & 1) * 8;
      unsigned int d01, d23, d45, d67;
      asm("v_cvt_pk_bf16_f32 %0, %1, %2" : "=v"(d01) : "v"(S[rb + 0]), "v"(S[rb + 1]));
      asm("v_cvt_pk_bf16_f32 %0, %1, %2" : "=v"(d23) : "v"(S[rb + 2]), "v"(S[rb + 3]));
      asm("v_cvt_pk_bf16_f32 %0, %1, %2" : "=v"(d45) : "v"(S[rb + 4]), "v"(S[rb + 5]));
      asm("v_cvt_pk_bf16_f32 %0, %1, %2" : "=v"(d67) : "v"(S[rb + 6]), "v"(S[rb + 7]));
      asm("v_permlane32_swap_b32 %0, %1" : "+v"(d01), "+v"(d45));
      asm("v_permlane32_swap_b32 %0, %1" : "+v"(d23), "+v"(d67));
      union { unsigned int u[4]; bf16x8 v; } t;
      t.u[0] = d01; t.u[1] = d23; t.u[2] = d45; t.u[3] = d67;
      pb[w] = t.v;
    }

    __builtin_amdgcn_s_setprio(1);
#pragma unroll
    for (int ks = 0; ks < 4; ++ks) {
      const int r0 = l32, r1 = 32 + l32;
      bf16x8 va0 = *reinterpret_cast<const bf16x8*>(
          &vb_[r0 * 128 + (((ks * 2 + hi) ^ (r0 & 7)) << 4)]);
      o0 = __builtin_amdgcn_mfma_f32_32x32x16_bf16(va0, pb[ks], o0, 0, 0, 0);
      bf16x8 va1 = *reinterpret_cast<const bf16x8*>(
          &vb_[r1 * 128 + (((ks * 2 + hi) ^ (r1 & 7)) << 4)]);
      o1 = __builtin_amdgcn_mfma_f32_32x32x16_bf16(va1, pb[ks], o1, 0, 0, 0);
    }
    __builtin_amdgcn_s_setprio(0);
  }

  float lrun = lsum + __shfl_xor(lsum, 32);
  float inv  = 1.0f / lrun;
  short* Orow = AO + ((int64_t)(b * 2048) + qrow) * 768 + h * 64;
#pragma unroll
  for (int dt = 0; dt < 2; ++dt) {
    const f32x16& O = dt ? o1 : o0;
#pragma unroll
    for (int rp = 0; rp < 8; ++rp) {
      int dbase = dt * 32 + (rp & 1) * 2 + (rp >> 1) * 8 + hi * 4;
      float a = O[2 * rp] * inv, bvl = O[2 * rp + 1] * inv;
      unsigned int wpk;
      asm("v_cvt_pk_bf16_f32 %0, %1, %2" : "=v"(wpk) : "v"(a), "v"(bvl));
      *reinterpret_cast<unsigned int*>(Orow + dbase) = wpk;
    }
  }
}

// ---------- launch ----------

extern "C" void kernel_launch(void* const* d_in, const int* in_sizes, int n_in,
                              void* d_out, int out_size, void* d_ws, size_t ws_size,
                              hipStream_t stream) {
  const float* x    = (const float*)d_in[0];
  const float* wqkv = (const float*)d_in[1];
  const float* wout = (const float*)d_in[2];
  const int*   mask = (const int*)d_in[3];
  float* out = (float*)d_out;

  char* ws = (char*)d_ws;
  short* Qb  = (short*)(ws + 0);          // 48*2048*64 bf16 = 12.58 MB
  short* Kb  = (short*)(ws + 12582912);   // compacted keys + zero tail
  short* VT  = (short*)(ws + 25165824);   // [bh][d][s'] compacted + zero tail
  short* Xbf = (short*)(ws + 37748736);   // x bf16; later reused as attn-out bf16
  short* Wq  = (short*)(ws + 50331648);
  short* Wo  = (short*)(ws + 53870592);
  int*   Pidx = (int*)(ws + 55050240);    // 4*2048 ints = 32 KB
  int*   Lens = (int*)(ws + 55083008);    // 4 ints

  cvt_scan<<<8452, 256, 0, stream>>>(x, Xbf, wqkv, Wq, wout, Wo,
                                     mask, Pidx, Lens, Kb, VT);

  gemm_bt<0><<<64 * 18, 256, 0, stream>>>(Xbf, Wq, nullptr, Qb, Kb, VT, Pidx,
                                          8192, 2304, 768);

  attn_kernel<<<48 * 16, 256, 0, stream>>>(Qb, Kb, VT, Lens, Xbf);

  gemm_bt<1><<<64 * 6, 256, 0, stream>>>(Xbf, Wo, out, nullptr, nullptr, nullptr,
                                         Pidx, 8192, 768, 768);
}

// Round 21
// 125.376 us; speedup vs baseline: 1.2402x; 1.0852x over previous
//
#include <hip/hip_runtime.h>
#include <hip/hip_bf16.h>
#include <stdint.h>

typedef __attribute__((ext_vector_type(4)))  float  f32x4;
typedef __attribute__((ext_vector_type(16))) float  f32x16;
typedef __attribute__((ext_vector_type(8)))  __bf16 bf16x8;
typedef __attribute__((ext_vector_type(4)))  float  float4_t;
typedef __attribute__((ext_vector_type(4)))  int    int4_t;

// ---------- helpers ----------

__device__ __forceinline__ short f2bf(float f) {
  uint32_t u = __builtin_bit_cast(uint32_t, f);
  return (short)((u + 0x7FFFu + ((u >> 16) & 1u)) >> 16);
}

__device__ __forceinline__ void gload16(const void* g, void* l) {
  __builtin_amdgcn_global_load_lds(
      (const __attribute__((address_space(1))) void*)g,
      (__attribute__((address_space(3))) void*)l, 16, 0, 0);
}

__device__ __forceinline__ bf16x8 frag_w0(unsigned int w0) {
  union { unsigned int u[4]; bf16x8 v; } t;
  t.u[0] = w0; t.u[1] = 0; t.u[2] = 0; t.u[3] = 0;
  return t.v;
}

// ---------- fused convert + mask scan ----------
// blocks [0,8448): fp32->bf16 convert. x and w_out straight; w_qkv rows are
// PERMUTED: feature f = h*192+c -> dstrow = c<64 ? h*64+c : 768+h*128+(c-64),
// giving contiguous B panels: [0,768) = Q features, [768,2304) = per-head KV.
// blocks [8448,8452): per-batch mask prefix scan -> invp (compacted idx ->
// source s) + lens. No tail zeroing needed: attention's key<len bias guard
// (-14400) forces p = 0 for padding keys regardless of K/V content.

__global__ void cvt_scan(const float* __restrict__ x,   short* __restrict__ xo,
                         const float* __restrict__ w1,  short* __restrict__ w1o,
                         const float* __restrict__ w2,  short* __restrict__ w2o,
                         const int* __restrict__ mask, int* __restrict__ invp,
                         int* __restrict__ lens) {
  const int tid = threadIdx.x;
  if (blockIdx.x >= 8448) {
    const int b = blockIdx.x - 8448;
    const int lane = tid & 63, wv = tid >> 6;
    __shared__ int wtot[4];
    const int* mb = mask + (b << 11);
    int4_t a = reinterpret_cast<const int4_t*>(mb)[tid * 2];
    int4_t c = reinterpret_cast<const int4_t*>(mb)[tid * 2 + 1];
    int m[8] = {a[0] ? 1 : 0, a[1] ? 1 : 0, a[2] ? 1 : 0, a[3] ? 1 : 0,
                c[0] ? 1 : 0, c[1] ? 1 : 0, c[2] ? 1 : 0, c[3] ? 1 : 0};
    int tsum = 0;
#pragma unroll
    for (int j = 0; j < 8; ++j) tsum += m[j];
    int inc = tsum;
#pragma unroll
    for (int d = 1; d < 64; d <<= 1) {
      int t = __shfl_up(inc, d);
      if (lane >= d) inc += t;
    }
    if (lane == 63) wtot[wv] = inc;
    __syncthreads();
    int woff = 0;
#pragma unroll
    for (int w = 0; w < 3; ++w) if (w < wv) woff += wtot[w];
    int run = woff + inc - tsum;
#pragma unroll
    for (int j = 0; j < 8; ++j) {
      if (m[j]) { invp[(b << 11) + run] = tid * 8 + j; run += 1; }
    }
    if (tid == 0) lens[b] = wtot[0] + wtot[1] + wtot[2] + wtot[3];
    return;
  }
  int i = blockIdx.x * 256 + tid;
  if (i < 1572864) {
    float4_t v = reinterpret_cast<const float4_t*>(x)[i];
    union { short s[4]; uint64_t u; } o;
    o.s[0] = f2bf(v[0]); o.s[1] = f2bf(v[1]);
    o.s[2] = f2bf(v[2]); o.s[3] = f2bf(v[3]);
    reinterpret_cast<uint64_t*>(xo)[i] = o.u;
  } else if (i < 2015232) {
    i -= 1572864;
    float4_t v = reinterpret_cast<const float4_t*>(w1)[i];
    union { short s[4]; uint64_t u; } o;
    o.s[0] = f2bf(v[0]); o.s[1] = f2bf(v[1]);
    o.s[2] = f2bf(v[2]); o.s[3] = f2bf(v[3]);
    int f = i / 192, k4 = i - f * 192;
    int h = f / 192, c = f - h * 192;
    int dstrow = (c < 64) ? (h * 64 + c) : (768 + h * 128 + (c - 64));
    reinterpret_cast<uint64_t*>(w1o)[dstrow * 192 + k4] = o.u;
  } else if (i < 2162688) {
    i -= 2015232;
    float4_t v = reinterpret_cast<const float4_t*>(w2)[i];
    union { short s[4]; uint64_t u; } o;
    o.s[0] = f2bf(v[0]); o.s[1] = f2bf(v[1]);
    o.s[2] = f2bf(v[2]); o.s[3] = f2bf(v[3]);
    reinterpret_cast<uint64_t*>(w2o)[i] = o.u;
  }
}

// ---------- fused Q + compacted-KV projection GEMM ----------
// R16/R20 pipeline (BK=32, 3-buffer 48KB, vmcnt(4), 2-ahead, XOR col swizzle).
// blocks [0,384): Q-path -- C[8192,768] = Xbf * WqQ^T, scatter to qb (scaled).
// blocks [384,1152): KV-path -- per (b, mtile, h): A rows gathered through
// invp (hoisted per-thread source pointers; &2047 keeps garbage in-bounds),
// B = per-head KV panel; writes compacted kb / transposed vtb. Early-exit
// for mtiles past ceil128(len[b]).

__global__ __launch_bounds__(256) void gemm_qkv(
    const short* __restrict__ A, const short* __restrict__ Bw,
    short* __restrict__ qb, short* __restrict__ kb, short* __restrict__ vtb,
    const int* __restrict__ invp, const int* __restrict__ lens)
{
  __shared__ __align__(16) short As[3][128 * 32];
  __shared__ __align__(16) short Bs[3][128 * 32];
  const int tid  = threadIdx.x;
  const int lane = tid & 63;
  const int wave = tid >> 6;
  const int wr   = wave >> 1, wc = wave & 1;
  const int l16  = lane & 15, lhi = lane >> 4;
  const int srow = lane >> 2;
  const int sg   = lane & 3;
  const int sgx  = (sg ^ ((srow >> 1) & 3)) * 8;
  const int K = 768;

  const bool isQ = blockIdx.x < 384;
  int bm, bn, b = 0;
  const short* aSrc0;
  const short* aSrc1;
  const short* bG;

  if (isQ) {
    const int nid = ((int)blockIdx.x & 7) * 48 + ((int)blockIdx.x >> 3);
    bm = nid / 6; bn = nid % 6;
    aSrc0 = A + (int64_t)(bm * 128 + wave * 32 + srow) * K + sgx;
    aSrc1 = aSrc0 + 16 * K;
    bG = Bw + (int64_t)(bn * 128) * K;
  } else {
    const int id  = (int)blockIdx.x - 384;
    const int nid = (id & 7) * 96 + (id >> 3);
    b = nid / 192;
    const int rem = nid - b * 192;
    bm = rem / 12; bn = rem % 12;              // bm = mtile in batch, bn = head
    const int len = lens[b];
    if (bm * 128 >= ((len + 127) & ~127)) return;
    const int base = (b << 11) + bm * 128 + wave * 32 + srow;
    int s0 = invp[base] & 2047;
    int s1 = invp[base + 16] & 2047;
    aSrc0 = A + (int64_t)((b << 11) + s0) * K + sgx;
    aSrc1 = A + (int64_t)((b << 11) + s1) * K + sgx;
    bG = Bw + (int64_t)(768 + bn * 128) * K;
  }

  f32x4 acc[4][4] = {};
  const int nt = 24;

  auto STAGE = [&](int buf, int t) {
    const int k0 = t * 32;
    gload16(aSrc0 + k0, &As[buf][(wave * 32) * 32 + lane * 8]);
    gload16(aSrc1 + k0, &As[buf][(wave * 32 + 16) * 32 + lane * 8]);
#pragma unroll
    for (int i = 0; i < 2; ++i) {
      int rr = wave * 32 + i * 16 + srow;
      gload16(bG + (int64_t)rr * K + k0 + sgx,
              &Bs[buf][(wave * 32 + i * 16) * 32 + lane * 8]);
    }
  };

  STAGE(0, 0);
  STAGE(1, 1);

  const int rga = (lhi ^ ((l16 >> 1) & 3)) << 3;

  for (int t = 0; t < nt; ++t) {
    if (t < nt - 1) asm volatile("s_waitcnt vmcnt(4)" ::: "memory");
    else            asm volatile("s_waitcnt vmcnt(0)" ::: "memory");
    __builtin_amdgcn_s_barrier();
    if (t + 2 < nt) STAGE((t + 2) % 3, t + 2);

    const short* as_ = As[t % 3];
    const short* bs_ = Bs[t % 3];
    bf16x8 af[4], bfr[4];
#pragma unroll
    for (int mi = 0; mi < 4; ++mi)
      af[mi] = *reinterpret_cast<const bf16x8*>(
          &as_[(wr * 64 + mi * 16 + l16) * 32 + rga]);
#pragma unroll
    for (int ni = 0; ni < 4; ++ni)
      bfr[ni] = *reinterpret_cast<const bf16x8*>(
          &bs_[(wc * 64 + ni * 16 + l16) * 32 + rga]);
#pragma unroll
    for (int mi = 0; mi < 4; ++mi)
#pragma unroll
      for (int ni = 0; ni < 4; ++ni)
        acc[mi][ni] = __builtin_amdgcn_mfma_f32_16x16x32_bf16(
            af[mi], bfr[ni], acc[mi][ni], 0, 0, 0);
  }

#pragma unroll
  for (int mi = 0; mi < 4; ++mi)
#pragma unroll
    for (int ni = 0; ni < 4; ++ni) {
#pragma unroll
      for (int r = 0; r < 4; ++r) {
        float v = acc[mi][ni][r];
        if (isQ) {
          int row = bm * 128 + wr * 64 + mi * 16 + lhi * 4 + r;
          int col = bn * 128 + wc * 64 + ni * 16 + l16;
          int bq = row >> 11, s = row & 2047;
          int h = col >> 6, d = col & 63;
          qb[(((bq * 12 + h) << 11) + s) * 64 + d] = f2bf(v * 0.18033688f);
        } else {
          int sp = bm * 128 + wr * 64 + mi * 16 + lhi * 4 + r;
          int cp = wc * 64 + ni * 16 + l16;
          int bh = b * 12 + bn;
          if (cp < 64) kb[((bh << 11) + sp) * 64 + cp] = f2bf(v);
          else         vtb[(((int64_t)bh * 64 + (cp - 64)) << 11) + sp] = f2bf(v);
        }
      }
    }
}

// ---------- out-projection GEMM (R20, unchanged) ----------

__global__ __launch_bounds__(256) void gemm_out(
    const short* __restrict__ A, const short* __restrict__ Bw,
    float* __restrict__ Cf, int M, int N, int K)
{
  __shared__ __align__(16) short As[3][128 * 32];
  __shared__ __align__(16) short Bs[3][128 * 32];
  const int tid  = threadIdx.x;
  const int lane = tid & 63;
  const int wave = tid >> 6;
  const int ntn  = N >> 7;
  const int cpx  = gridDim.x >> 3;
  const int nid  = (blockIdx.x & 7) * cpx + (blockIdx.x >> 3);
  const int bm   = nid / ntn;
  const int bn   = nid % ntn;
  const int wr   = wave >> 1, wc = wave & 1;
  const int l16  = lane & 15, lhi = lane >> 4;

  f32x4 acc[4][4] = {};

  const int srow = lane >> 2;
  const int sg   = lane & 3;
  const int sgx  = (sg ^ ((srow >> 1) & 3)) * 8;
  const short* aG = A  + (int64_t)(bm * 128) * K;
  const short* bG = Bw + (int64_t)(bn * 128) * K;
  const int nt = K >> 5;

  auto STAGE = [&](int buf, int t) {
    const int k0 = t * 32;
#pragma unroll
    for (int i = 0; i < 2; ++i) {
      int rr = wave * 32 + i * 16 + srow;
      gload16(aG + (int64_t)rr * K + k0 + sgx,
              &As[buf][(wave * 32 + i * 16) * 32 + lane * 8]);
      gload16(bG + (int64_t)rr * K + k0 + sgx,
              &Bs[buf][(wave * 32 + i * 16) * 32 + lane * 8]);
    }
  };

  STAGE(0, 0);
  STAGE(1, 1);

  const int rga = (lhi ^ ((l16 >> 1) & 3)) << 3;

  for (int t = 0; t < nt; ++t) {
    if (t < nt - 1) asm volatile("s_waitcnt vmcnt(4)" ::: "memory");
    else            asm volatile("s_waitcnt vmcnt(0)" ::: "memory");
    __builtin_amdgcn_s_barrier();
    if (t + 2 < nt) STAGE((t + 2) % 3, t + 2);

    const short* as_ = As[t % 3];
    const short* bs_ = Bs[t % 3];
    bf16x8 af[4], bfr[4];
#pragma unroll
    for (int mi = 0; mi < 4; ++mi)
      af[mi] = *reinterpret_cast<const bf16x8*>(
          &as_[(wr * 64 + mi * 16 + l16) * 32 + rga]);
#pragma unroll
    for (int ni = 0; ni < 4; ++ni)
      bfr[ni] = *reinterpret_cast<const bf16x8*>(
          &bs_[(wc * 64 + ni * 16 + l16) * 32 + rga]);
#pragma unroll
    for (int mi = 0; mi < 4; ++mi)
#pragma unroll
      for (int ni = 0; ni < 4; ++ni)
        acc[mi][ni] = __builtin_amdgcn_mfma_f32_16x16x32_bf16(
            af[mi], bfr[ni], acc[mi][ni], 0, 0, 0);
  }

#pragma unroll
  for (int mi = 0; mi < 4; ++mi)
#pragma unroll
    for (int ni = 0; ni < 4; ++ni) {
      int col = bn * 128 + wc * 64 + ni * 16 + l16;
#pragma unroll
      for (int r = 0; r < 4; ++r) {
        int row = bm * 128 + wr * 64 + mi * 16 + lhi * 4 + r;
        Cf[(int64_t)row * N + col] = acc[mi][ni][r];
      }
    }
}

// ---------- flash attention over COMPACTED K/V (R20, unchanged) ----------

__global__ __launch_bounds__(256, 2) void attn_kernel(
    const short* __restrict__ Qb, const short* __restrict__ Kb,
    const short* __restrict__ VTb, const int* __restrict__ lens,
    short* __restrict__ AO)
{
  __shared__ __align__(16) char Ks[3][8192];
  __shared__ __align__(16) char Vs[3][8192];

  const int tid  = threadIdx.x;
  const int lane = tid & 63;
  const int wave = tid >> 6;
  const int l32  = lane & 31;
  const int hi   = lane >> 5;

  const int blk  = blockIdx.x;
  const int xcd  = blk & 7;
  const int slot = blk >> 3;
  const int bh   = xcd * 6 + (slot % 6);
  const int qt   = slot / 6;
  const int b    = bh / 12, h = bh - b * 12;
  const int qrow = qt * 128 + wave * 32 + l32;

  const short* Qp  = Qb + ((int64_t)bh * 2048 + qrow) * 64;
  const char*  KpB = (const char*)(Kb + (int64_t)bh * 2048 * 64);
  const char*  VpB = (const char*)(VTb + (int64_t)bh * 64 * 2048);

  const int len = lens[b];
  const int nt  = (len + 63) >> 6;

  bf16x8 qf[4];
#pragma unroll
  for (int ks = 0; ks < 4; ++ks)
    qf[ks] = *reinterpret_cast<const bf16x8*>(Qp + ks * 16 + hi * 8);

  const int str = tid >> 3;
  const int stc = tid & 7;
  const char* kSrc[2]; const char* vSrc[2]; int ldst[2];
#pragma unroll
  for (int s = 0; s < 2; ++s) {
    int r  = s * 32 + str;
    int cx = (stc ^ (r & 7)) << 4;
    kSrc[s] = KpB + (int64_t)r * 128 + cx;
    vSrc[s] = VpB + (int64_t)r * 4096 + cx;
    ldst[s] = s * 4096 + tid * 16;
  }

  auto STAGE = [&](int buf, int k0) {
#pragma unroll
    for (int s = 0; s < 2; ++s) {
      gload16(kSrc[s] + (int64_t)k0 * 128, &Ks[buf][ldst[s]]);
      gload16(vSrc[s] + (int64_t)k0 * 2,   &Vs[buf][ldst[s]]);
    }
  };

  const bf16x8 qb5 = frag_w0(hi == 0 ? 0x3f80u : 0u);

  f32x16 o0 = {}, o1 = {};
  float lsum = 0.f;

  STAGE(0, 0);
  if (nt > 1) STAGE(1, 64);

  for (int kt = 0; kt < nt; ++kt) {
    const int cur = kt % 3;
    const int k0  = kt * 64;
    if (kt < nt - 1) asm volatile("s_waitcnt vmcnt(4)" ::: "memory");
    else             asm volatile("s_waitcnt vmcnt(0)" ::: "memory");
    __builtin_amdgcn_s_barrier();

    if (kt + 2 < nt) STAGE((kt + 2) % 3, (kt + 2) * 64);

    const char* kb_ = Ks[cur];
    const char* vb_ = Vs[cur];

    f32x16 st[2];
    __builtin_amdgcn_s_setprio(1);
#pragma unroll
    for (int kt2 = 0; kt2 < 2; ++kt2) {
      const int key = k0 + kt2 * 32 + l32;
      unsigned int bw = (key < len) ? 0xC140u : 0xC661u;
      f32x16 z = {};
      z = __builtin_amdgcn_mfma_f32_32x32x16_bf16(
              frag_w0(hi == 0 ? bw : 0u), qb5, z, 0, 0, 0);
      const int r = kt2 * 32 + l32;
#pragma unroll
      for (int ks = 0; ks < 4; ++ks) {
        bf16x8 kf = *reinterpret_cast<const bf16x8*>(
            &kb_[r * 128 + (((ks * 2 + hi) ^ (r & 7)) << 4)]);
        z = __builtin_amdgcn_mfma_f32_32x32x16_bf16(kf, qf[ks], z, 0, 0, 0);
      }
      st[kt2] = z;
    }
    __builtin_amdgcn_s_setprio(0);

    float psum = 0.f;
#pragma unroll
    for (int i = 0; i < 16; ++i) {
      float p = __builtin_amdgcn_exp2f(st[0][i]); st[0][i] = p; psum += p;
    }
#pragma unroll
    for (int i = 0; i < 16; ++i) {
      float p = __builtin_amdgcn_exp2f(st[1][i]); st[1][i] = p; psum += p;
    }
    lsum += psum;

    bf16x8 pb[4];
#pragma unroll
    for (int w = 0; w < 4; ++w) {
      const f32x16& S = st[w >> 1];
      const int rb = (w & 1) * 8;
      unsigned int d01, d23, d45, d67;
      asm("v_cvt_pk_bf16_f32 %0, %1, %2" : "=v"(d01) : "v"(S[rb + 0]), "v"(S[rb + 1]));
      asm("v_cvt_pk_bf16_f32 %0, %1, %2" : "=v"(d23) : "v"(S[rb + 2]), "v"(S[rb + 3]));
      asm("v_cvt_pk_bf16_f32 %0, %1, %2" : "=v"(d45) : "v"(S[rb + 4]), "v"(S[rb + 5]));
      asm("v_cvt_pk_bf16_f32 %0, %1, %2" : "=v"(d67) : "v"(S[rb + 6]), "v"(S[rb + 7]));
      asm("v_permlane32_swap_b32 %0, %1" : "+v"(d01), "+v"(d45));
      asm("v_permlane32_swap_b32 %0, %1" : "+v"(d23), "+v"(d67));
      union { unsigned int u[4]; bf16x8 v; } t;
      t.u[0] = d01; t.u[1] = d23; t.u[2] = d45; t.u[3] = d67;
      pb[w] = t.v;
    }

    __builtin_amdgcn_s_setprio(1);
#pragma unroll
    for (int ks = 0; ks < 4; ++ks) {
      const int r0 = l32, r1 = 32 + l32;
      bf16x8 va0 = *reinterpret_cast<const bf16x8*>(
          &vb_[r0 * 128 + (((ks * 2 + hi) ^ (r0 & 7)) << 4)]);
      o0 = __builtin_amdgcn_mfma_f32_32x32x16_bf16(va0, pb[ks], o0, 0, 0, 0);
      bf16x8 va1 = *reinterpret_cast<const bf16x8*>(
          &vb_[r1 * 128 + (((ks * 2 + hi) ^ (r1 & 7)) << 4)]);
      o1 = __builtin_amdgcn_mfma_f32_32x32x16_bf16(va1, pb[ks], o1, 0, 0, 0);
    }
    __builtin_amdgcn_s_setprio(0);
  }

  float lrun = lsum + __shfl_xor(lsum, 32);
  float inv  = 1.0f / lrun;
  short* Orow = AO + ((int64_t)(b * 2048) + qrow) * 768 + h * 64;
#pragma unroll
  for (int dt = 0; dt < 2; ++dt) {
    const f32x16& O = dt ? o1 : o0;
#pragma unroll
    for (int rp = 0; rp < 8; ++rp) {
      int dbase = dt * 32 + (rp & 1) * 2 + (rp >> 1) * 8 + hi * 4;
      float a = O[2 * rp] * inv, bvl = O[2 * rp + 1] * inv;
      unsigned int wpk;
      asm("v_cvt_pk_bf16_f32 %0, %1, %2" : "=v"(wpk) : "v"(a), "v"(bvl));
      *reinterpret_cast<unsigned int*>(Orow + dbase) = wpk;
    }
  }
}

// ---------- launch ----------

extern "C" void kernel_launch(void* const* d_in, const int* in_sizes, int n_in,
                              void* d_out, int out_size, void* d_ws, size_t ws_size,
                              hipStream_t stream) {
  const float* x    = (const float*)d_in[0];
  const float* wqkv = (const float*)d_in[1];
  const float* wout = (const float*)d_in[2];
  const int*   mask = (const int*)d_in[3];
  float* out = (float*)d_out;

  char* ws = (char*)d_ws;
  short* Qb  = (short*)(ws + 0);          // 12.58 MB
  short* Kb  = (short*)(ws + 12582912);   // compacted keys
  short* VT  = (short*)(ws + 25165824);   // [bh][d][s'] compacted
  short* Xbf = (short*)(ws + 37748736);   // x bf16; reused as attn-out bf16
  short* Wq  = (short*)(ws + 50331648);   // permuted: [Q 768 | KV 1536] rows
  short* Wo  = (short*)(ws + 53870592);
  int*   Invp = (int*)(ws + 55050240);    // 4*2048 ints
  int*   Lens = (int*)(ws + 55083008);    // 4 ints

  cvt_scan<<<8452, 256, 0, stream>>>(x, Xbf, wqkv, Wq, wout, Wo,
                                     mask, Invp, Lens);

  gemm_qkv<<<1152, 256, 0, stream>>>(Xbf, Wq, Qb, Kb, VT, Invp, Lens);

  attn_kernel<<<48 * 16, 256, 0, stream>>>(Qb, Kb, VT, Lens, Xbf);

  gemm_out<<<64 * 6, 256, 0, stream>>>(Xbf, Wo, out, 8192, 768, 768);
}

// Round 22
// 121.634 us; speedup vs baseline: 1.2783x; 1.0308x over previous
//
#include <hip/hip_runtime.h>
#include <hip/hip_bf16.h>
#include <stdint.h>

typedef __attribute__((ext_vector_type(4)))  float  f32x4;
typedef __attribute__((ext_vector_type(16))) float  f32x16;
typedef __attribute__((ext_vector_type(8)))  __bf16 bf16x8;
typedef __attribute__((ext_vector_type(4)))  float  float4_t;
typedef __attribute__((ext_vector_type(4)))  int    int4_t;

// ---------- helpers ----------

__device__ __forceinline__ short f2bf(float f) {
  uint32_t u = __builtin_bit_cast(uint32_t, f);
  return (short)((u + 0x7FFFu + ((u >> 16) & 1u)) >> 16);
}

__device__ __forceinline__ void gload16(const void* g, void* l) {
  __builtin_amdgcn_global_load_lds(
      (const __attribute__((address_space(1))) void*)g,
      (__attribute__((address_space(3))) void*)l, 16, 0, 0);
}

__device__ __forceinline__ bf16x8 frag_w0(unsigned int w0) {
  union { unsigned int u[4]; bf16x8 v; } t;
  t.u[0] = w0; t.u[1] = 0; t.u[2] = 0; t.u[3] = 0;
  return t.v;
}

// ---------- fused convert + mask scan ----------
// blocks [0,8448): fp32->bf16 convert. x and w_out straight; w_qkv rows are
// PERMUTED: feature f = h*192+c -> dstrow = c<64 ? h*64+c : 768+h*128+(c-64),
// giving contiguous B panels: [0,768) = Q features, [768,2304) = per-head KV.
// blocks [8448,8452): per-batch mask prefix scan -> invp (compacted idx ->
// source s) + lens. No tail zeroing needed: attention's key<len bias guard
// (-14400) forces p = 0 for padding keys regardless of K/V content.

__global__ void cvt_scan(const float* __restrict__ x,   short* __restrict__ xo,
                         const float* __restrict__ w1,  short* __restrict__ w1o,
                         const float* __restrict__ w2,  short* __restrict__ w2o,
                         const int* __restrict__ mask, int* __restrict__ invp,
                         int* __restrict__ lens) {
  const int tid = threadIdx.x;
  if (blockIdx.x >= 8448) {
    const int b = blockIdx.x - 8448;
    const int lane = tid & 63, wv = tid >> 6;
    __shared__ int wtot[4];
    const int* mb = mask + (b << 11);
    int4_t a = reinterpret_cast<const int4_t*>(mb)[tid * 2];
    int4_t c = reinterpret_cast<const int4_t*>(mb)[tid * 2 + 1];
    int m[8] = {a[0] ? 1 : 0, a[1] ? 1 : 0, a[2] ? 1 : 0, a[3] ? 1 : 0,
                c[0] ? 1 : 0, c[1] ? 1 : 0, c[2] ? 1 : 0, c[3] ? 1 : 0};
    int tsum = 0;
#pragma unroll
    for (int j = 0; j < 8; ++j) tsum += m[j];
    int inc = tsum;
#pragma unroll
    for (int d = 1; d < 64; d <<= 1) {
      int t = __shfl_up(inc, d);
      if (lane >= d) inc += t;
    }
    if (lane == 63) wtot[wv] = inc;
    __syncthreads();
    int woff = 0;
#pragma unroll
    for (int w = 0; w < 3; ++w) if (w < wv) woff += wtot[w];
    int run = woff + inc - tsum;
#pragma unroll
    for (int j = 0; j < 8; ++j) {
      if (m[j]) { invp[(b << 11) + run] = tid * 8 + j; run += 1; }
    }
    if (tid == 0) lens[b] = wtot[0] + wtot[1] + wtot[2] + wtot[3];
    return;
  }
  int i = blockIdx.x * 256 + tid;
  if (i < 1572864) {
    float4_t v = reinterpret_cast<const float4_t*>(x)[i];
    union { short s[4]; uint64_t u; } o;
    o.s[0] = f2bf(v[0]); o.s[1] = f2bf(v[1]);
    o.s[2] = f2bf(v[2]); o.s[3] = f2bf(v[3]);
    reinterpret_cast<uint64_t*>(xo)[i] = o.u;
  } else if (i < 2015232) {
    i -= 1572864;
    float4_t v = reinterpret_cast<const float4_t*>(w1)[i];
    union { short s[4]; uint64_t u; } o;
    o.s[0] = f2bf(v[0]); o.s[1] = f2bf(v[1]);
    o.s[2] = f2bf(v[2]); o.s[3] = f2bf(v[3]);
    int f = i / 192, k4 = i - f * 192;
    int h = f / 192, c = f - h * 192;
    int dstrow = (c < 64) ? (h * 64 + c) : (768 + h * 128 + (c - 64));
    reinterpret_cast<uint64_t*>(w1o)[dstrow * 192 + k4] = o.u;
  } else if (i < 2162688) {
    i -= 2015232;
    float4_t v = reinterpret_cast<const float4_t*>(w2)[i];
    union { short s[4]; uint64_t u; } o;
    o.s[0] = f2bf(v[0]); o.s[1] = f2bf(v[1]);
    o.s[2] = f2bf(v[2]); o.s[3] = f2bf(v[3]);
    reinterpret_cast<uint64_t*>(w2o)[i] = o.u;
  }
}

// ---------- fused Q + compacted-KV projection GEMM ----------
// R16/R20 pipeline (BK=32, 3-buffer 48KB, vmcnt(4), 2-ahead, XOR col swizzle).
// blocks [0,384): Q-path. blocks [384,1152): KV-path with DEAD-LAST ordering:
// id = bm*48 + b*12 + bn (bm-major), so inactive mtiles (bm past each batch's
// ceil128(len)) are the grid TAIL -- they dispatch after the active work has
// filled round 1 and retire instantly, instead of R21's XCD-interleave that
// parked dead blocks in round-1 slots (occ 14%, 1.5 effective rounds).

__global__ __launch_bounds__(256) void gemm_qkv(
    const short* __restrict__ A, const short* __restrict__ Bw,
    short* __restrict__ qb, short* __restrict__ kb, short* __restrict__ vtb,
    const int* __restrict__ invp, const int* __restrict__ lens)
{
  __shared__ __align__(16) short As[3][128 * 32];
  __shared__ __align__(16) short Bs[3][128 * 32];
  const int tid  = threadIdx.x;
  const int lane = tid & 63;
  const int wave = tid >> 6;
  const int wr   = wave >> 1, wc = wave & 1;
  const int l16  = lane & 15, lhi = lane >> 4;
  const int srow = lane >> 2;
  const int sg   = lane & 3;
  const int sgx  = (sg ^ ((srow >> 1) & 3)) * 8;
  const int K = 768;

  const bool isQ = blockIdx.x < 384;
  int bm, bn, b = 0;
  const short* aSrc0;
  const short* aSrc1;
  const short* bG;

  if (isQ) {
    const int nid = ((int)blockIdx.x & 7) * 48 + ((int)blockIdx.x >> 3);
    bm = nid / 6; bn = nid % 6;
    aSrc0 = A + (int64_t)(bm * 128 + wave * 32 + srow) * K + sgx;
    aSrc1 = aSrc0 + 16 * K;
    bG = Bw + (int64_t)(bn * 128) * K;
  } else {
    const int id = (int)blockIdx.x - 384;
    bm = id / 48;                          // bm-major: dead mtiles last
    const int rem = id - bm * 48;
    b = rem / 12; bn = rem % 12;
    const int len = lens[b];
    if (bm * 128 >= ((len + 127) & ~127)) return;
    const int base = (b << 11) + bm * 128 + wave * 32 + srow;
    int s0 = invp[base] & 2047;
    int s1 = invp[base + 16] & 2047;
    aSrc0 = A + (int64_t)((b << 11) + s0) * K + sgx;
    aSrc1 = A + (int64_t)((b << 11) + s1) * K + sgx;
    bG = Bw + (int64_t)(768 + bn * 128) * K;
  }

  f32x4 acc[4][4] = {};
  const int nt = 24;

  auto STAGE = [&](int buf, int t) {
    const int k0 = t * 32;
    gload16(aSrc0 + k0, &As[buf][(wave * 32) * 32 + lane * 8]);
    gload16(aSrc1 + k0, &As[buf][(wave * 32 + 16) * 32 + lane * 8]);
#pragma unroll
    for (int i = 0; i < 2; ++i) {
      int rr = wave * 32 + i * 16 + srow;
      gload16(bG + (int64_t)rr * K + k0 + sgx,
              &Bs[buf][(wave * 32 + i * 16) * 32 + lane * 8]);
    }
  };

  STAGE(0, 0);
  STAGE(1, 1);

  const int rga = (lhi ^ ((l16 >> 1) & 3)) << 3;

  for (int t = 0; t < nt; ++t) {
    if (t < nt - 1) asm volatile("s_waitcnt vmcnt(4)" ::: "memory");
    else            asm volatile("s_waitcnt vmcnt(0)" ::: "memory");
    __builtin_amdgcn_s_barrier();
    if (t + 2 < nt) STAGE((t + 2) % 3, t + 2);

    const short* as_ = As[t % 3];
    const short* bs_ = Bs[t % 3];
    bf16x8 af[4], bfr[4];
#pragma unroll
    for (int mi = 0; mi < 4; ++mi)
      af[mi] = *reinterpret_cast<const bf16x8*>(
          &as_[(wr * 64 + mi * 16 + l16) * 32 + rga]);
#pragma unroll
    for (int ni = 0; ni < 4; ++ni)
      bfr[ni] = *reinterpret_cast<const bf16x8*>(
          &bs_[(wc * 64 + ni * 16 + l16) * 32 + rga]);
#pragma unroll
    for (int mi = 0; mi < 4; ++mi)
#pragma unroll
      for (int ni = 0; ni < 4; ++ni)
        acc[mi][ni] = __builtin_amdgcn_mfma_f32_16x16x32_bf16(
            af[mi], bfr[ni], acc[mi][ni], 0, 0, 0);
  }

#pragma unroll
  for (int mi = 0; mi < 4; ++mi)
#pragma unroll
    for (int ni = 0; ni < 4; ++ni) {
#pragma unroll
      for (int r = 0; r < 4; ++r) {
        float v = acc[mi][ni][r];
        if (isQ) {
          int row = bm * 128 + wr * 64 + mi * 16 + lhi * 4 + r;
          int col = bn * 128 + wc * 64 + ni * 16 + l16;
          int bq = row >> 11, s = row & 2047;
          int h = col >> 6, d = col & 63;
          qb[(((bq * 12 + h) << 11) + s) * 64 + d] = f2bf(v * 0.18033688f);
        } else {
          int sp = bm * 128 + wr * 64 + mi * 16 + lhi * 4 + r;
          int cp = wc * 64 + ni * 16 + l16;
          int bh = b * 12 + bn;
          if (cp < 64) kb[((bh << 11) + sp) * 64 + cp] = f2bf(v);
          else         vtb[(((int64_t)bh * 64 + (cp - 64)) << 11) + sp] = f2bf(v);
        }
      }
    }
}

// ---------- out-projection GEMM (unchanged) ----------

__global__ __launch_bounds__(256) void gemm_out(
    const short* __restrict__ A, const short* __restrict__ Bw,
    float* __restrict__ Cf, int M, int N, int K)
{
  __shared__ __align__(16) short As[3][128 * 32];
  __shared__ __align__(16) short Bs[3][128 * 32];
  const int tid  = threadIdx.x;
  const int lane = tid & 63;
  const int wave = tid >> 6;
  const int ntn  = N >> 7;
  const int cpx  = gridDim.x >> 3;
  const int nid  = (blockIdx.x & 7) * cpx + (blockIdx.x >> 3);
  const int bm   = nid / ntn;
  const int bn   = nid % ntn;
  const int wr   = wave >> 1, wc = wave & 1;
  const int l16  = lane & 15, lhi = lane >> 4;

  f32x4 acc[4][4] = {};

  const int srow = lane >> 2;
  const int sg   = lane & 3;
  const int sgx  = (sg ^ ((srow >> 1) & 3)) * 8;
  const short* aG = A  + (int64_t)(bm * 128) * K;
  const short* bG = Bw + (int64_t)(bn * 128) * K;
  const int nt = K >> 5;

  auto STAGE = [&](int buf, int t) {
    const int k0 = t * 32;
#pragma unroll
    for (int i = 0; i < 2; ++i) {
      int rr = wave * 32 + i * 16 + srow;
      gload16(aG + (int64_t)rr * K + k0 + sgx,
              &As[buf][(wave * 32 + i * 16) * 32 + lane * 8]);
      gload16(bG + (int64_t)rr * K + k0 + sgx,
              &Bs[buf][(wave * 32 + i * 16) * 32 + lane * 8]);
    }
  };

  STAGE(0, 0);
  STAGE(1, 1);

  const int rga = (lhi ^ ((l16 >> 1) & 3)) << 3;

  for (int t = 0; t < nt; ++t) {
    if (t < nt - 1) asm volatile("s_waitcnt vmcnt(4)" ::: "memory");
    else            asm volatile("s_waitcnt vmcnt(0)" ::: "memory");
    __builtin_amdgcn_s_barrier();
    if (t + 2 < nt) STAGE((t + 2) % 3, t + 2);

    const short* as_ = As[t % 3];
    const short* bs_ = Bs[t % 3];
    bf16x8 af[4], bfr[4];
#pragma unroll
    for (int mi = 0; mi < 4; ++mi)
      af[mi] = *reinterpret_cast<const bf16x8*>(
          &as_[(wr * 64 + mi * 16 + l16) * 32 + rga]);
#pragma unroll
    for (int ni = 0; ni < 4; ++ni)
      bfr[ni] = *reinterpret_cast<const bf16x8*>(
          &bs_[(wc * 64 + ni * 16 + l16) * 32 + rga]);
#pragma unroll
    for (int mi = 0; mi < 4; ++mi)
#pragma unroll
      for (int ni = 0; ni < 4; ++ni)
        acc[mi][ni] = __builtin_amdgcn_mfma_f32_16x16x32_bf16(
            af[mi], bfr[ni], acc[mi][ni], 0, 0, 0);
  }

#pragma unroll
  for (int mi = 0; mi < 4; ++mi)
#pragma unroll
    for (int ni = 0; ni < 4; ++ni) {
      int col = bn * 128 + wc * 64 + ni * 16 + l16;
#pragma unroll
      for (int r = 0; r < 4; ++r) {
        int row = bm * 128 + wr * 64 + mi * 16 + lhi * 4 + r;
        Cf[(int64_t)row * N + col] = acc[mi][ni][r];
      }
    }
}

// ---------- flash attention over COMPACTED K/V (unchanged) ----------

__global__ __launch_bounds__(256, 2) void attn_kernel(
    const short* __restrict__ Qb, const short* __restrict__ Kb,
    const short* __restrict__ VTb, const int* __restrict__ lens,
    short* __restrict__ AO)
{
  __shared__ __align__(16) char Ks[3][8192];
  __shared__ __align__(16) char Vs[3][8192];

  const int tid  = threadIdx.x;
  const int lane = tid & 63;
  const int wave = tid >> 6;
  const int l32  = lane & 31;
  const int hi   = lane >> 5;

  const int blk  = blockIdx.x;
  const int xcd  = blk & 7;
  const int slot = blk >> 3;
  const int bh   = xcd * 6 + (slot % 6);
  const int qt   = slot / 6;
  const int b    = bh / 12, h = bh - b * 12;
  const int qrow = qt * 128 + wave * 32 + l32;

  const short* Qp  = Qb + ((int64_t)bh * 2048 + qrow) * 64;
  const char*  KpB = (const char*)(Kb + (int64_t)bh * 2048 * 64);
  const char*  VpB = (const char*)(VTb + (int64_t)bh * 64 * 2048);

  const int len = lens[b];
  const int nt  = (len + 63) >> 6;

  bf16x8 qf[4];
#pragma unroll
  for (int ks = 0; ks < 4; ++ks)
    qf[ks] = *reinterpret_cast<const bf16x8*>(Qp + ks * 16 + hi * 8);

  const int str = tid >> 3;
  const int stc = tid & 7;
  const char* kSrc[2]; const char* vSrc[2]; int ldst[2];
#pragma unroll
  for (int s = 0; s < 2; ++s) {
    int r  = s * 32 + str;
    int cx = (stc ^ (r & 7)) << 4;
    kSrc[s] = KpB + (int64_t)r * 128 + cx;
    vSrc[s] = VpB + (int64_t)r * 4096 + cx;
    ldst[s] = s * 4096 + tid * 16;
  }

  auto STAGE = [&](int buf, int k0) {
#pragma unroll
    for (int s = 0; s < 2; ++s) {
      gload16(kSrc[s] + (int64_t)k0 * 128, &Ks[buf][ldst[s]]);
      gload16(vSrc[s] + (int64_t)k0 * 2,   &Vs[buf][ldst[s]]);
    }
  };

  const bf16x8 qb5 = frag_w0(hi == 0 ? 0x3f80u : 0u);

  f32x16 o0 = {}, o1 = {};
  float lsum = 0.f;

  STAGE(0, 0);
  if (nt > 1) STAGE(1, 64);

  for (int kt = 0; kt < nt; ++kt) {
    const int cur = kt % 3;
    const int k0  = kt * 64;
    if (kt < nt - 1) asm volatile("s_waitcnt vmcnt(4)" ::: "memory");
    else             asm volatile("s_waitcnt vmcnt(0)" ::: "memory");
    __builtin_amdgcn_s_barrier();

    if (kt + 2 < nt) STAGE((kt + 2) % 3, (kt + 2) * 64);

    const char* kb_ = Ks[cur];
    const char* vb_ = Vs[cur];

    f32x16 st[2];
    __builtin_amdgcn_s_setprio(1);
#pragma unroll
    for (int kt2 = 0; kt2 < 2; ++kt2) {
      const int key = k0 + kt2 * 32 + l32;
      unsigned int bw = (key < len) ? 0xC140u : 0xC661u;
      f32x16 z = {};
      z = __builtin_amdgcn_mfma_f32_32x32x16_bf16(
              frag_w0(hi == 0 ? bw : 0u), qb5, z, 0, 0, 0);
      const int r = kt2 * 32 + l32;
#pragma unroll
      for (int ks = 0; ks < 4; ++ks) {
        bf16x8 kf = *reinterpret_cast<const bf16x8*>(
            &kb_[r * 128 + (((ks * 2 + hi) ^ (r & 7)) << 4)]);
        z = __builtin_amdgcn_mfma_f32_32x32x16_bf16(kf, qf[ks], z, 0, 0, 0);
      }
      st[kt2] = z;
    }
    __builtin_amdgcn_s_setprio(0);

    float psum = 0.f;
#pragma unroll
    for (int i = 0; i < 16; ++i) {
      float p = __builtin_amdgcn_exp2f(st[0][i]); st[0][i] = p; psum += p;
    }
#pragma unroll
    for (int i = 0; i < 16; ++i) {
      float p = __builtin_amdgcn_exp2f(st[1][i]); st[1][i] = p; psum += p;
    }
    lsum += psum;

    bf16x8 pb[4];
#pragma unroll
    for (int w = 0; w < 4; ++w) {
      const f32x16& S = st[w >> 1];
      const int rb = (w & 1) * 8;
      unsigned int d01, d23, d45, d67;
      asm("v_cvt_pk_bf16_f32 %0, %1, %2" : "=v"(d01) : "v"(S[rb + 0]), "v"(S[rb + 1]));
      asm("v_cvt_pk_bf16_f32 %0, %1, %2" : "=v"(d23) : "v"(S[rb + 2]), "v"(S[rb + 3]));
      asm("v_cvt_pk_bf16_f32 %0, %1, %2" : "=v"(d45) : "v"(S[rb + 4]), "v"(S[rb + 5]));
      asm("v_cvt_pk_bf16_f32 %0, %1, %2" : "=v"(d67) : "v"(S[rb + 6]), "v"(S[rb + 7]));
      asm("v_permlane32_swap_b32 %0, %1" : "+v"(d01), "+v"(d45));
      asm("v_permlane32_swap_b32 %0, %1" : "+v"(d23), "+v"(d67));
      union { unsigned int u[4]; bf16x8 v; } t;
      t.u[0] = d01; t.u[1] = d23; t.u[2] = d45; t.u[3] = d67;
      pb[w] = t.v;
    }

    __builtin_amdgcn_s_setprio(1);
#pragma unroll
    for (int ks = 0; ks < 4; ++ks) {
      const int r0 = l32, r1 = 32 + l32;
      bf16x8 va0 = *reinterpret_cast<const bf16x8*>(
          &vb_[r0 * 128 + (((ks * 2 + hi) ^ (r0 & 7)) << 4)]);
      o0 = __builtin_amdgcn_mfma_f32_32x32x16_bf16(va0, pb[ks], o0, 0, 0, 0);
      bf16x8 va1 = *reinterpret_cast<const bf16x8*>(
          &vb_[r1 * 128 + (((ks * 2 + hi) ^ (r1 & 7)) << 4)]);
      o1 = __builtin_amdgcn_mfma_f32_32x32x16_bf16(va1, pb[ks], o1, 0, 0, 0);
    }
    __builtin_amdgcn_s_setprio(0);
  }

  float lrun = lsum + __shfl_xor(lsum, 32);
  float inv  = 1.0f / lrun;
  short* Orow = AO + ((int64_t)(b * 2048) + qrow) * 768 + h * 64;
#pragma unroll
  for (int dt = 0; dt < 2; ++dt) {
    const f32x16& O = dt ? o1 : o0;
#pragma unroll
    for (int rp = 0; rp < 8; ++rp) {
      int dbase = dt * 32 + (rp & 1) * 2 + (rp >> 1) * 8 + hi * 4;
      float a = O[2 * rp] * inv, bvl = O[2 * rp + 1] * inv;
      unsigned int wpk;
      asm("v_cvt_pk_bf16_f32 %0, %1, %2" : "=v"(wpk) : "v"(a), "v"(bvl));
      *reinterpret_cast<unsigned int*>(Orow + dbase) = wpk;
    }
  }
}

// ---------- launch ----------

extern "C" void kernel_launch(void* const* d_in, const int* in_sizes, int n_in,
                              void* d_out, int out_size, void* d_ws, size_t ws_size,
                              hipStream_t stream) {
  const float* x    = (const float*)d_in[0];
  const float* wqkv = (const float*)d_in[1];
  const float* wout = (const float*)d_in[2];
  const int*   mask = (const int*)d_in[3];
  float* out = (float*)d_out;

  char* ws = (char*)d_ws;
  short* Qb  = (short*)(ws + 0);          // 12.58 MB
  short* Kb  = (short*)(ws + 12582912);   // compacted keys
  short* VT  = (short*)(ws + 25165824);   // [bh][d][s'] compacted
  short* Xbf = (short*)(ws + 37748736);   // x bf16; reused as attn-out bf16
  short* Wq  = (short*)(ws + 50331648);   // permuted: [Q 768 | KV 1536] rows
  short* Wo  = (short*)(ws + 53870592);
  int*   Invp = (int*)(ws + 55050240);    // 4*2048 ints
  int*   Lens = (int*)(ws + 55083008);    // 4 ints

  cvt_scan<<<8452, 256, 0, stream>>>(x, Xbf, wqkv, Wq, wout, Wo,
                                     mask, Invp, Lens);

  gemm_qkv<<<1152, 256, 0, stream>>>(Xbf, Wq, Qb, Kb, VT, Invp, Lens);

  attn_kernel<<<48 * 16, 256, 0, stream>>>(Qb, Kb, VT, Lens, Xbf);

  gemm_out<<<64 * 6, 256, 0, stream>>>(Xbf, Wo, out, 8192, 768, 768);
}

// Round 23
// 118.625 us; speedup vs baseline: 1.3108x; 1.0254x over previous
//
#include <hip/hip_runtime.h>
#include <hip/hip_bf16.h>
#include <stdint.h>

typedef __attribute__((ext_vector_type(4)))  float  f32x4;
typedef __attribute__((ext_vector_type(16))) float  f32x16;
typedef __attribute__((ext_vector_type(8)))  __bf16 bf16x8;
typedef __attribute__((ext_vector_type(4)))  float  float4_t;
typedef __attribute__((ext_vector_type(4)))  int    int4_t;

// ---------- helpers ----------

__device__ __forceinline__ short f2bf(float f) {
  uint32_t u = __builtin_bit_cast(uint32_t, f);
  return (short)((u + 0x7FFFu + ((u >> 16) & 1u)) >> 16);
}

__device__ __forceinline__ void gload16(const void* g, void* l) {
  __builtin_amdgcn_global_load_lds(
      (const __attribute__((address_space(1))) void*)g,
      (__attribute__((address_space(3))) void*)l, 16, 0, 0);
}

__device__ __forceinline__ bf16x8 frag_w0(unsigned int w0) {
  union { unsigned int u[4]; bf16x8 v; } t;
  t.u[0] = w0; t.u[1] = 0; t.u[2] = 0; t.u[3] = 0;
  return t.v;
}

// ---------- fused convert + mask scan (unchanged) ----------

__global__ void cvt_scan(const float* __restrict__ x,   short* __restrict__ xo,
                         const float* __restrict__ w1,  short* __restrict__ w1o,
                         const float* __restrict__ w2,  short* __restrict__ w2o,
                         const int* __restrict__ mask, int* __restrict__ invp,
                         int* __restrict__ lens) {
  const int tid = threadIdx.x;
  if (blockIdx.x >= 8448) {
    const int b = blockIdx.x - 8448;
    const int lane = tid & 63, wv = tid >> 6;
    __shared__ int wtot[4];
    const int* mb = mask + (b << 11);
    int4_t a = reinterpret_cast<const int4_t*>(mb)[tid * 2];
    int4_t c = reinterpret_cast<const int4_t*>(mb)[tid * 2 + 1];
    int m[8] = {a[0] ? 1 : 0, a[1] ? 1 : 0, a[2] ? 1 : 0, a[3] ? 1 : 0,
                c[0] ? 1 : 0, c[1] ? 1 : 0, c[2] ? 1 : 0, c[3] ? 1 : 0};
    int tsum = 0;
#pragma unroll
    for (int j = 0; j < 8; ++j) tsum += m[j];
    int inc = tsum;
#pragma unroll
    for (int d = 1; d < 64; d <<= 1) {
      int t = __shfl_up(inc, d);
      if (lane >= d) inc += t;
    }
    if (lane == 63) wtot[wv] = inc;
    __syncthreads();
    int woff = 0;
#pragma unroll
    for (int w = 0; w < 3; ++w) if (w < wv) woff += wtot[w];
    int run = woff + inc - tsum;
#pragma unroll
    for (int j = 0; j < 8; ++j) {
      if (m[j]) { invp[(b << 11) + run] = tid * 8 + j; run += 1; }
    }
    if (tid == 0) lens[b] = wtot[0] + wtot[1] + wtot[2] + wtot[3];
    return;
  }
  int i = blockIdx.x * 256 + tid;
  if (i < 1572864) {
    float4_t v = reinterpret_cast<const float4_t*>(x)[i];
    union { short s[4]; uint64_t u; } o;
    o.s[0] = f2bf(v[0]); o.s[1] = f2bf(v[1]);
    o.s[2] = f2bf(v[2]); o.s[3] = f2bf(v[3]);
    reinterpret_cast<uint64_t*>(xo)[i] = o.u;
  } else if (i < 2015232) {
    i -= 1572864;
    float4_t v = reinterpret_cast<const float4_t*>(w1)[i];
    union { short s[4]; uint64_t u; } o;
    o.s[0] = f2bf(v[0]); o.s[1] = f2bf(v[1]);
    o.s[2] = f2bf(v[2]); o.s[3] = f2bf(v[3]);
    int f = i / 192, k4 = i - f * 192;
    int h = f / 192, c = f - h * 192;
    int dstrow = (c < 64) ? (h * 64 + c) : (768 + h * 128 + (c - 64));
    reinterpret_cast<uint64_t*>(w1o)[dstrow * 192 + k4] = o.u;
  } else if (i < 2162688) {
    i -= 2015232;
    float4_t v = reinterpret_cast<const float4_t*>(w2)[i];
    union { short s[4]; uint64_t u; } o;
    o.s[0] = f2bf(v[0]); o.s[1] = f2bf(v[1]);
    o.s[2] = f2bf(v[2]); o.s[3] = f2bf(v[3]);
    reinterpret_cast<uint64_t*>(w2o)[i] = o.u;
  }
}

// ---------- fused Q + compacted-KV projection, 256x128 tile ----------
// R23: BM=256 x BN=128, 4 waves (2x2; each wave owns 128x64 = 32 MFMA/iter,
// 2x the 128^2 structure's per-wave density -- the m102 small-K plateau fix).
// BK=32, 3-buffer LDS (72 KB -> 2 blocks/CU), counted vmcnt(6) (6 loads/
// thread/tile: 4 A-passes + 2 B-passes), loads 2 tiles ahead. Same XOR col
// swizzle (A-source sgx is pass-invariant: i*64 rows == 0 mod 4).
// blocks [0,192): Q-path (M=8192 x N=768; XCD-chunked). blocks [192,576):
// KV-path (per batch, compacted rows via invp; one head per bn; bm-major
// dead-last; early-exit past len).

__global__ __launch_bounds__(256) void gemm_qkv(
    const short* __restrict__ A, const short* __restrict__ Bw,
    short* __restrict__ qb, short* __restrict__ kb, short* __restrict__ vtb,
    const int* __restrict__ invp, const int* __restrict__ lens)
{
  __shared__ __align__(16) short As[3][256 * 32];
  __shared__ __align__(16) short Bs[3][128 * 32];
  const int tid  = threadIdx.x;
  const int lane = tid & 63;
  const int wave = tid >> 6;
  const int wrh  = wave >> 1;        // 0..1: M half (128 rows)
  const int wcq  = wave & 1;         // 0..1: N half (64 cols)
  const int l16  = lane & 15, lhi = lane >> 4;
  const int K = 768;

  // staging geometry: thread covers row (pass*64 + tid>>2), col-group tid&3
  const int strow = tid >> 2;        // 0..63
  const int sgx   = ((tid & 3) ^ ((tid >> 3) & 3)) * 8;   // swizzled col (shorts)

  const bool isQ = blockIdx.x < 192;
  int bm, bn, b = 0;
  const short* aSrc[4];
  const short* bG;

  if (isQ) {
    const int nid = ((int)blockIdx.x & 7) * 24 + ((int)blockIdx.x >> 3);
    bm = nid / 6; bn = nid % 6;
#pragma unroll
    for (int i = 0; i < 4; ++i)
      aSrc[i] = A + (int64_t)(bm * 256 + i * 64 + strow) * K + sgx;
    bG = Bw + (int64_t)(bn * 128) * K;
  } else {
    const int id = (int)blockIdx.x - 192;
    bm = id / 48;                    // bm-major: dead mtiles last
    const int rem = id - bm * 48;
    b = rem / 12; bn = rem % 12;     // bn = head
    const int len = lens[b];
    if (bm * 256 >= len) return;
#pragma unroll
    for (int i = 0; i < 4; ++i) {
      int s = invp[(b << 11) + ((bm * 256 + i * 64 + strow) & 2047)] & 2047;
      aSrc[i] = A + (int64_t)((b << 11) + s) * K + sgx;
    }
    bG = Bw + (int64_t)(768 + bn * 128) * K;
  }

  f32x4 acc[8][4] = {};
  const int nt = 24;

  auto STAGE = [&](int buf, int t) {
    const int k0 = t * 32;
#pragma unroll
    for (int i = 0; i < 4; ++i)
      gload16(aSrc[i] + k0, &As[buf][(i * 64 + strow) * 32 + (tid & 3) * 8]);
#pragma unroll
    for (int j = 0; j < 2; ++j)
      gload16(bG + (int64_t)(j * 64 + strow) * K + k0 + sgx,
              &Bs[buf][(j * 64 + strow) * 32 + (tid & 3) * 8]);
  };

  STAGE(0, 0);
  STAGE(1, 1);

  const int rga = (lhi ^ ((l16 >> 1) & 3)) << 3;

  for (int t = 0; t < nt; ++t) {
    if (t < nt - 1) asm volatile("s_waitcnt vmcnt(6)" ::: "memory");
    else            asm volatile("s_waitcnt vmcnt(0)" ::: "memory");
    __builtin_amdgcn_s_barrier();
    if (t + 2 < nt) STAGE((t + 2) % 3, t + 2);

    const short* as_ = As[t % 3];
    const short* bs_ = Bs[t % 3];
    bf16x8 af[8], bfr[4];
#pragma unroll
    for (int mi = 0; mi < 8; ++mi)
      af[mi] = *reinterpret_cast<const bf16x8*>(
          &as_[(wrh * 128 + mi * 16 + l16) * 32 + rga]);
#pragma unroll
    for (int ni = 0; ni < 4; ++ni)
      bfr[ni] = *reinterpret_cast<const bf16x8*>(
          &bs_[(wcq * 64 + ni * 16 + l16) * 32 + rga]);
#pragma unroll
    for (int mi = 0; mi < 8; ++mi)
#pragma unroll
      for (int ni = 0; ni < 4; ++ni)
        acc[mi][ni] = __builtin_amdgcn_mfma_f32_16x16x32_bf16(
            af[mi], bfr[ni], acc[mi][ni], 0, 0, 0);
  }

#pragma unroll
  for (int mi = 0; mi < 8; ++mi)
#pragma unroll
    for (int ni = 0; ni < 4; ++ni) {
      int col = bn * 128 + wcq * 64 + ni * 16 + l16;
#pragma unroll
      for (int r = 0; r < 4; ++r) {
        float v = acc[mi][ni][r];
        int rloc = wrh * 128 + mi * 16 + lhi * 4 + r;
        if (isQ) {
          int row = bm * 256 + rloc;
          int bq = row >> 11, s = row & 2047;
          int h = col >> 6, d = col & 63;
          qb[(((bq * 12 + h) << 11) + s) * 64 + d] = f2bf(v * 0.18033688f);
        } else {
          int sp = bm * 256 + rloc;            // row in compacted batch space
          int c  = col & 127;                  // head = bn
          int bh = b * 12 + bn;
          if (c < 64) kb[((bh << 11) + sp) * 64 + c] = f2bf(v);
          else        vtb[(((int64_t)bh * 64 + (c - 64)) << 11) + sp] = f2bf(v);
        }
      }
    }
}

// ---------- out-projection GEMM (R20 128^2, unchanged) ----------

__global__ __launch_bounds__(256) void gemm_out(
    const short* __restrict__ A, const short* __restrict__ Bw,
    float* __restrict__ Cf, int M, int N, int K)
{
  __shared__ __align__(16) short As[3][128 * 32];
  __shared__ __align__(16) short Bs[3][128 * 32];
  const int tid  = threadIdx.x;
  const int lane = tid & 63;
  const int wave = tid >> 6;
  const int ntn  = N >> 7;
  const int cpx  = gridDim.x >> 3;
  const int nid  = (blockIdx.x & 7) * cpx + (blockIdx.x >> 3);
  const int bm   = nid / ntn;
  const int bn   = nid % ntn;
  const int wr   = wave >> 1, wc = wave & 1;
  const int l16  = lane & 15, lhi = lane >> 4;

  f32x4 acc[4][4] = {};

  const int srow = lane >> 2;
  const int sg   = lane & 3;
  const int sgx  = (sg ^ ((srow >> 1) & 3)) * 8;
  const short* aG = A  + (int64_t)(bm * 128) * K;
  const short* bG = Bw + (int64_t)(bn * 128) * K;
  const int nt = K >> 5;

  auto STAGE = [&](int buf, int t) {
    const int k0 = t * 32;
#pragma unroll
    for (int i = 0; i < 2; ++i) {
      int rr = wave * 32 + i * 16 + srow;
      gload16(aG + (int64_t)rr * K + k0 + sgx,
              &As[buf][(wave * 32 + i * 16) * 32 + lane * 8]);
      gload16(bG + (int64_t)rr * K + k0 + sgx,
              &Bs[buf][(wave * 32 + i * 16) * 32 + lane * 8]);
    }
  };

  STAGE(0, 0);
  STAGE(1, 1);

  const int rga = (lhi ^ ((l16 >> 1) & 3)) << 3;

  for (int t = 0; t < nt; ++t) {
    if (t < nt - 1) asm volatile("s_waitcnt vmcnt(4)" ::: "memory");
    else            asm volatile("s_waitcnt vmcnt(0)" ::: "memory");
    __builtin_amdgcn_s_barrier();
    if (t + 2 < nt) STAGE((t + 2) % 3, t + 2);

    const short* as_ = As[t % 3];
    const short* bs_ = Bs[t % 3];
    bf16x8 af[4], bfr[4];
#pragma unroll
    for (int mi = 0; mi < 4; ++mi)
      af[mi] = *reinterpret_cast<const bf16x8*>(
          &as_[(wr * 64 + mi * 16 + l16) * 32 + rga]);
#pragma unroll
    for (int ni = 0; ni < 4; ++ni)
      bfr[ni] = *reinterpret_cast<const bf16x8*>(
          &bs_[(wc * 64 + ni * 16 + l16) * 32 + rga]);
#pragma unroll
    for (int mi = 0; mi < 4; ++mi)
#pragma unroll
      for (int ni = 0; ni < 4; ++ni)
        acc[mi][ni] = __builtin_amdgcn_mfma_f32_16x16x32_bf16(
            af[mi], bfr[ni], acc[mi][ni], 0, 0, 0);
  }

#pragma unroll
  for (int mi = 0; mi < 4; ++mi)
#pragma unroll
    for (int ni = 0; ni < 4; ++ni) {
      int col = bn * 128 + wc * 64 + ni * 16 + l16;
#pragma unroll
      for (int r = 0; r < 4; ++r) {
        int row = bm * 128 + wr * 64 + mi * 16 + lhi * 4 + r;
        Cf[(int64_t)row * N + col] = acc[mi][ni][r];
      }
    }
}

// ---------- flash attention over COMPACTED K/V (unchanged) ----------

__global__ __launch_bounds__(256, 2) void attn_kernel(
    const short* __restrict__ Qb, const short* __restrict__ Kb,
    const short* __restrict__ VTb, const int* __restrict__ lens,
    short* __restrict__ AO)
{
  __shared__ __align__(16) char Ks[3][8192];
  __shared__ __align__(16) char Vs[3][8192];

  const int tid  = threadIdx.x;
  const int lane = tid & 63;
  const int wave = tid >> 6;
  const int l32  = lane & 31;
  const int hi   = lane >> 5;

  const int blk  = blockIdx.x;
  const int xcd  = blk & 7;
  const int slot = blk >> 3;
  const int bh   = xcd * 6 + (slot % 6);
  const int qt   = slot / 6;
  const int b    = bh / 12, h = bh - b * 12;
  const int qrow = qt * 128 + wave * 32 + l32;

  const short* Qp  = Qb + ((int64_t)bh * 2048 + qrow) * 64;
  const char*  KpB = (const char*)(Kb + (int64_t)bh * 2048 * 64);
  const char*  VpB = (const char*)(VTb + (int64_t)bh * 64 * 2048);

  const int len = lens[b];
  const int nt  = (len + 63) >> 6;

  bf16x8 qf[4];
#pragma unroll
  for (int ks = 0; ks < 4; ++ks)
    qf[ks] = *reinterpret_cast<const bf16x8*>(Qp + ks * 16 + hi * 8);

  const int str = tid >> 3;
  const int stc = tid & 7;
  const char* kSrc[2]; const char* vSrc[2]; int ldst[2];
#pragma unroll
  for (int s = 0; s < 2; ++s) {
    int r  = s * 32 + str;
    int cx = (stc ^ (r & 7)) << 4;
    kSrc[s] = KpB + (int64_t)r * 128 + cx;
    vSrc[s] = VpB + (int64_t)r * 4096 + cx;
    ldst[s] = s * 4096 + tid * 16;
  }

  auto STAGE = [&](int buf, int k0) {
#pragma unroll
    for (int s = 0; s < 2; ++s) {
      gload16(kSrc[s] + (int64_t)k0 * 128, &Ks[buf][ldst[s]]);
      gload16(vSrc[s] + (int64_t)k0 * 2,   &Vs[buf][ldst[s]]);
    }
  };

  const bf16x8 qb5 = frag_w0(hi == 0 ? 0x3f80u : 0u);

  f32x16 o0 = {}, o1 = {};
  float lsum = 0.f;

  STAGE(0, 0);
  if (nt > 1) STAGE(1, 64);

  for (int kt = 0; kt < nt; ++kt) {
    const int cur = kt % 3;
    const int k0  = kt * 64;
    if (kt < nt - 1) asm volatile("s_waitcnt vmcnt(4)" ::: "memory");
    else             asm volatile("s_waitcnt vmcnt(0)" ::: "memory");
    __builtin_amdgcn_s_barrier();

    if (kt + 2 < nt) STAGE((kt + 2) % 3, (kt + 2) * 64);

    const char* kb_ = Ks[cur];
    const char* vb_ = Vs[cur];

    f32x16 st[2];
    __builtin_amdgcn_s_setprio(1);
#pragma unroll
    for (int kt2 = 0; kt2 < 2; ++kt2) {
      const int key = k0 + kt2 * 32 + l32;
      unsigned int bw = (key < len) ? 0xC140u : 0xC661u;
      f32x16 z = {};
      z = __builtin_amdgcn_mfma_f32_32x32x16_bf16(
              frag_w0(hi == 0 ? bw : 0u), qb5, z, 0, 0, 0);
      const int r = kt2 * 32 + l32;
#pragma unroll
      for (int ks = 0; ks < 4; ++ks) {
        bf16x8 kf = *reinterpret_cast<const bf16x8*>(
            &kb_[r * 128 + (((ks * 2 + hi) ^ (r & 7)) << 4)]);
        z = __builtin_amdgcn_mfma_f32_32x32x16_bf16(kf, qf[ks], z, 0, 0, 0);
      }
      st[kt2] = z;
    }
    __builtin_amdgcn_s_setprio(0);

    float psum = 0.f;
#pragma unroll
    for (int i = 0; i < 16; ++i) {
      float p = __builtin_amdgcn_exp2f(st[0][i]); st[0][i] = p; psum += p;
    }
#pragma unroll
    for (int i = 0; i < 16; ++i) {
      float p = __builtin_amdgcn_exp2f(st[1][i]); st[1][i] = p; psum += p;
    }
    lsum += psum;

    bf16x8 pb[4];
#pragma unroll
    for (int w = 0; w < 4; ++w) {
      const f32x16& S = st[w >> 1];
      const int rb = (w & 1) * 8;
      unsigned int d01, d23, d45, d67;
      asm("v_cvt_pk_bf16_f32 %0, %1, %2" : "=v"(d01) : "v"(S[rb + 0]), "v"(S[rb + 1]));
      asm("v_cvt_pk_bf16_f32 %0, %1, %2" : "=v"(d23) : "v"(S[rb + 2]), "v"(S[rb + 3]));
      asm("v_cvt_pk_bf16_f32 %0, %1, %2" : "=v"(d45) : "v"(S[rb + 4]), "v"(S[rb + 5]));
      asm("v_cvt_pk_bf16_f32 %0, %1, %2" : "=v"(d67) : "v"(S[rb + 6]), "v"(S[rb + 7]));
      asm("v_permlane32_swap_b32 %0, %1" : "+v"(d01), "+v"(d45));
      asm("v_permlane32_swap_b32 %0, %1" : "+v"(d23), "+v"(d67));
      union { unsigned int u[4]; bf16x8 v; } t;
      t.u[0] = d01; t.u[1] = d23; t.u[2] = d45; t.u[3] = d67;
      pb[w] = t.v;
    }

    __builtin_amdgcn_s_setprio(1);
#pragma unroll
    for (int ks = 0; ks < 4; ++ks) {
      const int r0 = l32, r1 = 32 + l32;
      bf16x8 va0 = *reinterpret_cast<const bf16x8*>(
          &vb_[r0 * 128 + (((ks * 2 + hi) ^ (r0 & 7)) << 4)]);
      o0 = __builtin_amdgcn_mfma_f32_32x32x16_bf16(va0, pb[ks], o0, 0, 0, 0);
      bf16x8 va1 = *reinterpret_cast<const bf16x8*>(
          &vb_[r1 * 128 + (((ks * 2 + hi) ^ (r1 & 7)) << 4)]);
      o1 = __builtin_amdgcn_mfma_f32_32x32x16_bf16(va1, pb[ks], o1, 0, 0, 0);
    }
    __builtin_amdgcn_s_setprio(0);
  }

  float lrun = lsum + __shfl_xor(lsum, 32);
  float inv  = 1.0f / lrun;
  short* Orow = AO + ((int64_t)(b * 2048) + qrow) * 768 + h * 64;
#pragma unroll
  for (int dt = 0; dt < 2; ++dt) {
    const f32x16& O = dt ? o1 : o0;
#pragma unroll
    for (int rp = 0; rp < 8; ++rp) {
      int dbase = dt * 32 + (rp & 1) * 2 + (rp >> 1) * 8 + hi * 4;
      float a = O[2 * rp] * inv, bvl = O[2 * rp + 1] * inv;
      unsigned int wpk;
      asm("v_cvt_pk_bf16_f32 %0, %1, %2" : "=v"(wpk) : "v"(a), "v"(bvl));
      *reinterpret_cast<unsigned int*>(Orow + dbase) = wpk;
    }
  }
}

// ---------- launch ----------

extern "C" void kernel_launch(void* const* d_in, const int* in_sizes, int n_in,
                              void* d_out, int out_size, void* d_ws, size_t ws_size,
                              hipStream_t stream) {
  const float* x    = (const float*)d_in[0];
  const float* wqkv = (const float*)d_in[1];
  const float* wout = (const float*)d_in[2];
  const int*   mask = (const int*)d_in[3];
  float* out = (float*)d_out;

  char* ws = (char*)d_ws;
  short* Qb  = (short*)(ws + 0);          // 12.58 MB
  short* Kb  = (short*)(ws + 12582912);   // compacted keys
  short* VT  = (short*)(ws + 25165824);   // [bh][d][s'] compacted
  short* Xbf = (short*)(ws + 37748736);   // x bf16; reused as attn-out bf16
  short* Wq  = (short*)(ws + 50331648);   // permuted: [Q 768 | KV 1536] rows
  short* Wo  = (short*)(ws + 53870592);
  int*   Invp = (int*)(ws + 55050240);    // 4*2048 ints
  int*   Lens = (int*)(ws + 55083008);    // 4 ints

  cvt_scan<<<8452, 256, 0, stream>>>(x, Xbf, wqkv, Wq, wout, Wo,
                                     mask, Invp, Lens);

  gemm_qkv<<<576, 256, 0, stream>>>(Xbf, Wq, Qb, Kb, VT, Invp, Lens);

  attn_kernel<<<48 * 16, 256, 0, stream>>>(Qb, Kb, VT, Lens, Xbf);

  gemm_out<<<64 * 6, 256, 0, stream>>>(Xbf, Wo, out, 8192, 768, 768);
}